// Round 9
// baseline (1063.700 us; speedup 1.0000x reference)
//
#include <hip/hip_runtime.h>
#include <cstddef>

constexpr int NB   = 512;  // batch
constexpr int ND   = 512;  // dim
constexpr int NL   = 32;   // context length
constexpr int NHW  = 196;  // knowledge spatial
constexpr int NK   = 8;    // history slots
constexpr int NSTEP = 4;

typedef __attribute__((ext_vector_type(8))) short short8v;
typedef __attribute__((ext_vector_type(4))) float f32x4;

__device__ __forceinline__ void splitbf(float x, short& h, short& l) {
    unsigned u  = __float_as_uint(x);
    unsigned hb = (u + 0x7FFFu + ((u >> 16) & 1u)) & 0xFFFF0000u;
    h = (short)(hb >> 16);
    float rem = x - __uint_as_float(hb);
    unsigned v = __float_as_uint(rem);
    l = (short)((v + 0x7FFFu + ((v >> 16) & 1u)) >> 16);
}
__device__ __forceinline__ unsigned short f2bf(float x) {
    unsigned u = __float_as_uint(x);
    return (unsigned short)((u + 0x7FFFu + ((u >> 16) & 1u)) >> 16);
}
__device__ __forceinline__ float bf2f(unsigned short h) {
    return __uint_as_float(((unsigned)h) << 16);
}

// =====================================================================
// LDS-staged grouped split-bf16 MFMA GEMM (R5 structure, BK=32).
//  C = act(concat(A1,A2) @ Bw^T + bias); A,B pre-split bf16 hi/lo planes.
//  full=1: 3-pass (fp32-accurate). full=0: 2-pass (drops B-lo term —
//  bf16-level weight precision; used only for softmax/sigmoid-bound GEMMs).
//  Block = 256 thr (4 waves as 2Mx2N), tile 32(M) x 64(N) x 32(K).
//  LDS rows padded to 40 shorts. ldc = C row stride.
// =====================================================================
struct GP {
    const short *A1h, *A1l, *A2h, *A2l, *Bh, *Bl;
    const float* bias;
    float* C; short* Ch; short* Cl;
    int lda1, lda2, k1, N, K, ntN, t0, act, ldc, full;
};
struct GPG { GP p[3]; int np; };

__device__ void dev_gemm(const GP& p, int local, int t, char* smem)
{
    short (*Ah)[40]   = (short(*)[40])(smem);
    short (*Al)[40]   = (short(*)[40])(smem + 2560);
    short (*Bh_s)[40] = (short(*)[40])(smem + 5120);
    short (*Bl_s)[40] = (short(*)[40])(smem + 10240);
    const int my = local / p.ntN, nx = local - my * p.ntN;
    const int m0 = my * 32, n0 = nx * 64;
    const int lane = t & 63, wid = t >> 6;
    const int wr = wid >> 1, wc = wid & 1;
    const int lr = lane & 15, lk = (lane >> 4) * 8;
    const int ar = (t & 127) >> 2, ak = (t & 3) * 8;
    const bool alo = t >= 128;
    const int br = t >> 2, bk = (t & 3) * 8;

    f32x4 acc0 = {}, acc1 = {};
    for (int kt = 0; kt < p.K; kt += 32) {
        {
            const int gk = kt + ak;
            const short* srcp = (gk < p.k1)
                ? (alo ? p.A1l : p.A1h) + (size_t)(m0 + ar) * p.lda1 + gk
                : (alo ? p.A2l : p.A2h) + (size_t)(m0 + ar) * p.lda2 + (gk - p.k1);
            short8v v = *(const short8v*)srcp;
            if (alo) *(short8v*)&Al[ar][ak] = v;
            else     *(short8v*)&Ah[ar][ak] = v;
        }
        {
            const size_t off = (size_t)(n0 + br) * p.K + kt + bk;
            *(short8v*)&Bh_s[br][bk] = *(const short8v*)(p.Bh + off);
            if (p.full)
                *(short8v*)&Bl_s[br][bk] = *(const short8v*)(p.Bl + off);
        }
        __syncthreads();
        short8v ah  = *(short8v*)&Ah[wr * 16 + lr][lk];
        short8v al  = *(short8v*)&Al[wr * 16 + lr][lk];
        short8v bh0 = *(short8v*)&Bh_s[wc * 32      + lr][lk];
        short8v bh1 = *(short8v*)&Bh_s[wc * 32 + 16 + lr][lk];
        acc0 = __builtin_amdgcn_mfma_f32_16x16x32_bf16(ah, bh0, acc0, 0, 0, 0);
        acc1 = __builtin_amdgcn_mfma_f32_16x16x32_bf16(ah, bh1, acc1, 0, 0, 0);
        acc0 = __builtin_amdgcn_mfma_f32_16x16x32_bf16(al, bh0, acc0, 0, 0, 0);
        acc1 = __builtin_amdgcn_mfma_f32_16x16x32_bf16(al, bh1, acc1, 0, 0, 0);
        if (p.full) {
            short8v bl0 = *(short8v*)&Bl_s[wc * 32      + lr][lk];
            short8v bl1 = *(short8v*)&Bl_s[wc * 32 + 16 + lr][lk];
            acc0 = __builtin_amdgcn_mfma_f32_16x16x32_bf16(ah, bl0, acc0, 0, 0, 0);
            acc1 = __builtin_amdgcn_mfma_f32_16x16x32_bf16(ah, bl1, acc1, 0, 0, 0);
        }
        __syncthreads();
    }
    const int r0 = m0 + wr * 16 + ((lane >> 4) << 2);
    const int cb = n0 + wc * 32 + lr;
    #pragma unroll
    for (int fc = 0; fc < 2; ++fc) {
        const f32x4& a = fc ? acc1 : acc0;
        const int col = cb + fc * 16;
        const float badd = p.bias ? p.bias[col] : 0.f;
        #pragma unroll
        for (int rr = 0; rr < 4; ++rr) {
            float x = a[rr] + badd;
            if (p.act == 1) x = (x > 0.f) ? x : (expf(x) - 1.f);
            const size_t idx = (size_t)(r0 + rr) * p.ldc + col;
            if (p.C) p.C[idx] = x;
            if (p.Ch) { short h, l; splitbf(x, h, l); p.Ch[idx] = h; p.Cl[idx] = l; }
        }
    }
}

__global__ __launch_bounds__(256) void ggemm_k(GPG g)
{
    __shared__ __align__(16) char smem[15360];
    const int bid = blockIdx.x;
    int pi = 0;
    if (g.np > 1 && bid >= g.p[1].t0) pi = 1;
    if (g.np > 2 && bid >= g.p[2].t0) pi = 2;
    dev_gemm(g.p[pi], bid - g.p[pi].t0, threadIdx.x, smem);
}

// =====================================================================
// Weight/activation conversion prologue (R5): fp32 -> bf16 hi/lo
// =====================================================================
struct WSeg { const float* src; short* dh; short* dl; int n; };
struct WTab { WSeg s[12]; int total; };

__global__ __launch_bounds__(256) void wconv_k(WTab tab)
{
    int i = blockIdx.x * 256 + threadIdx.x;
    if (i >= tab.total) return;
    int seg = 0, off = i;
    while (off >= tab.s[seg].n) { off -= tab.s[seg].n; ++seg; }
    short h, l; splitbf(tab.s[seg].src[off], h, l);
    tab.s[seg].dh[off] = h;
    tab.s[seg].dl[off] = l;
}

__global__ __launch_bounds__(256) void tconv_k(
    const float* s0, short* dh0, short* dl0,
    const float* s1, short* dh1, short* dl1)
{
    const float* src = blockIdx.z ? s1 : s0;
    short* dh = blockIdx.z ? dh1 : dh0;
    short* dl = blockIdx.z ? dl1 : dl0;
    __shared__ float tile[32][33];
    const int n0 = blockIdx.x * 32, k0 = blockIdx.y * 32;
    const int tx = threadIdx.x & 31, ty = threadIdx.x >> 5;
    for (int i = ty; i < 32; i += 8)
        tile[i][tx] = src[(size_t)(k0 + i) * 1024 + n0 + tx];
    __syncthreads();
    for (int i = ty; i < 32; i += 8) {
        short h, l; splitbf(tile[tx][i], h, l);
        dh[(size_t)(n0 + i) * 512 + k0 + tx] = h;
        dl[(size_t)(n0 + i) * 512 + k0 + tx] = l;
    }
}

// =====================================================================
// Control attention (R5): 512 threads, one block per batch element.
// =====================================================================
__global__ __launch_bounds__(512) void ctrl_attn_k(
    const float* __restrict__ cqi, const float* __restrict__ context,
    const float* __restrict__ attn_w, const float* __restrict__ read_attn_w,
    const float* __restrict__ rm_attn_w,
    short* __restrict__ ct_h, short* __restrict__ ct_l,
    short* __restrict__ cw_h, short* __restrict__ cw_l,
    short* __restrict__ cx_h, short* __restrict__ cx_l)
{
    const int b = blockIdx.x, t = threadIdx.x;
    const int lane = t & 63, w = t >> 6;
    __shared__ float q[ND];
    __shared__ float p[NL];
    const float* ctx = context + (size_t)b * NL * ND;

    q[t] = cqi[(size_t)b * ND + t] * attn_w[t];
    __syncthreads();

    for (int l = w; l < NL; l += 8) {
        float s = 0.f;
        const float* row = ctx + (size_t)l * ND;
        #pragma unroll
        for (int d = lane; d < ND; d += 64) s += q[d] * row[d];
        #pragma unroll
        for (int o = 32; o; o >>= 1) s += __shfl_down(s, o);
        if (lane == 0) p[l] = s;
    }
    __syncthreads();
    if (t == 0) {
        float mx = p[0];
        for (int l = 1; l < NL; ++l) mx = fmaxf(mx, p[l]);
        float sum = 0.f;
        for (int l = 0; l < NL; ++l) { float e = expf(p[l] - mx); p[l] = e; sum += e; }
        const float inv = 1.f / sum;
        for (int l = 0; l < NL; ++l) p[l] *= inv;
    }
    __syncthreads();
    float a = 0.f;
    #pragma unroll 8
    for (int l = 0; l < NL; ++l) a += p[l] * ctx[(size_t)l * ND + t];
    const size_t ix = (size_t)b * ND + t;
    short h, l2;
    splitbf(a, h, l2);                     ct_h[ix] = h; ct_l[ix] = l2;
    splitbf(a * read_attn_w[t], h, l2);    cw_h[ix] = h; cw_l[ix] = l2;
    splitbf(a * rm_attn_w[t],  h, l2);     cx_h[ix] = h; cx_l[ix] = l2;
}

// =====================================================================
// Merged kb_score + hist_attn (R5).
// =====================================================================
template<int FIRST>
__global__ __launch_bounds__(256) void kbsh_k(
    const float* __restrict__ kbp_f32, unsigned short* __restrict__ kbp_bf,
    const float* __restrict__ mpc, const float* __restrict__ u,
    float* __restrict__ s_part,
    const float* __restrict__ hist, const float* __restrict__ uh,
    float* __restrict__ rvi, float* __restrict__ read_h,
    short* __restrict__ rh_h, short* __restrict__ rh_l)
{
    __shared__ float sh[NK * ND + ND];
    __shared__ float sred[NK], pk[NK];
    const int bx = blockIdx.x, t = threadIdx.x;
    const int lane = t & 63, w = t >> 6;

    if (bx < 4 * NB) {
        const int jc = bx >> 9, b = bx & 511;
        float* v = sh;
        const int j0 = jc * 128;
        if (t < 128) {
            const int j = j0 + t;
            v[t] = mpc[(size_t)b * 1024 + j] * u[(size_t)b * 1024 + j]
                 + u[(size_t)b * 1024 + 512 + j];
        }
        __syncthreads();
        if (t < NHW) {
            const size_t base = (size_t)b * ND * NHW + (size_t)j0 * NHW + t;
            float s = 0.f;
            #pragma unroll 4
            for (int j = 0; j < 128; ++j) {
                float x;
                if (FIRST) {
                    x = kbp_f32[base + (size_t)j * NHW];
                    kbp_bf[base + (size_t)j * NHW] = f2bf(x);
                } else {
                    x = bf2f(kbp_bf[base + (size_t)j * NHW]);
                }
                s += x * v[j];
            }
            s_part[((size_t)jc * NB + b) * 200 + t] = s;
        }
    } else {
        const int b = bx - 4 * NB;
        float* ht = sh;
        float* vh = sh + NK * ND;
        const float* hb = hist + (size_t)b * ND * NK;

        for (int dd = t; dd < ND; dd += 256) {
            float4 h0 = *(const float4*)&hb[(size_t)dd * NK];
            float4 h1 = *(const float4*)&hb[(size_t)dd * NK + 4];
            ht[0 * ND + dd] = h0.x; ht[1 * ND + dd] = h0.y;
            ht[2 * ND + dd] = h0.z; ht[3 * ND + dd] = h0.w;
            ht[4 * ND + dd] = h1.x; ht[5 * ND + dd] = h1.y;
            ht[6 * ND + dd] = h1.z; ht[7 * ND + dd] = h1.w;
            vh[dd] = mpc[(size_t)b * 1024 + 512 + dd] * uh[(size_t)b * 1024 + dd]
                   + uh[(size_t)b * 1024 + 512 + dd];
        }
        __syncthreads();

        for (int k = w; k < NK; k += 4) {
            float s = 0.f;
            #pragma unroll 4
            for (int dd = lane; dd < ND; dd += 64) s += ht[k * ND + dd] * vh[dd];
            #pragma unroll
            for (int o = 32; o; o >>= 1) s += __shfl_down(s, o);
            if (lane == 0) sred[k] = s;
        }
        __syncthreads();
        if (t == 0) {
            float mx = sred[0];
            #pragma unroll
            for (int k = 1; k < NK; ++k) mx = fmaxf(mx, sred[k]);
            float ev[NK]; float sum = 0.f;
            #pragma unroll
            for (int k = 0; k < NK; ++k) { ev[k] = expf(sred[k] - mx); sum += ev[k]; }
            const float inv = 1.f / sum;
            #pragma unroll
            for (int k = 0; k < NK; ++k) { float pv = ev[k] * inv; pk[k] = pv; rvi[(size_t)b * NK + k] = pv; }
        }
        __syncthreads();
        for (int dd = t; dd < ND; dd += 256) {
            float a = 0.f;
            #pragma unroll
            for (int k = 0; k < NK; ++k) a += pk[k] * ht[k * ND + dd];
            const size_t ix = (size_t)b * ND + dd;
            read_h[ix] = a;
            short h, l; splitbf(a, h, l);
            rh_h[ix] = h; rh_l[ix] = l;
        }
    }
}

// =====================================================================
// KB read (R5).
// =====================================================================
template<int FIRST>
__global__ __launch_bounds__(256) void kb_read_k(
    const float* __restrict__ knw_f32, unsigned short* __restrict__ knw_bf,
    const float* __restrict__ s_part,
    float* __restrict__ readv, short* __restrict__ rv_h, short* __restrict__ rv_l)
{
    const int dcb = blockIdx.x, b = blockIdx.y, t = threadIdx.x;
    const int lane = t & 63, w = t >> 6;
    __shared__ float ps[200];
    __shared__ float red[8];

    float val = -INFINITY;
    if (t < NHW) {
        float sp = 0.f;
        #pragma unroll
        for (int jc = 0; jc < 4; ++jc) sp += s_part[((size_t)jc * NB + b) * 200 + t];
        val = sp;
    }
    float mx = val;
    #pragma unroll
    for (int o = 32; o; o >>= 1) mx = fmaxf(mx, __shfl_xor(mx, o));
    if (lane == 0) red[w] = mx;
    __syncthreads();
    mx = fmaxf(fmaxf(red[0], red[1]), fmaxf(red[2], red[3]));
    const float e = (t < NHW) ? expf(val - mx) : 0.f;
    float sm = e;
    #pragma unroll
    for (int o = 32; o; o >>= 1) sm += __shfl_xor(sm, o);
    if (lane == 0) red[4 + w] = sm;
    __syncthreads();
    const float tot = red[4] + red[5] + red[6] + red[7];
    if (t < 200) ps[t] = (t < NHW) ? e / tot : 0.f;
    __syncthreads();

    const int d1 = dcb * 64 + 64;
    for (int d = dcb * 64 + w; d < d1; d += 4) {
        const size_t rbase = (size_t)b * ND * NHW + (size_t)d * NHW;
        float a = 0.f;
        for (int h = lane; h < NHW; h += 64) {
            float x;
            if (FIRST) {
                x = knw_f32[rbase + h];
                knw_bf[rbase + h] = f2bf(x);
            } else {
                x = bf2f(knw_bf[rbase + h]);
            }
            a += ps[h] * x;
        }
        #pragma unroll
        for (int o = 32; o; o >>= 1) a += __shfl_down(a, o);
        if (lane == 0) {
            const size_t ix = (size_t)b * ND + d;
            readv[ix] = a;
            short h2, l2; splitbf(a, h2, l2);
            rv_h[ix] = h2; rv_l[ix] = l2;
        }
    }
}

// =====================================================================
// Merged scalars + state update (R5).
// =====================================================================
__global__ __launch_bounds__(256) void update2_k(
    const float* __restrict__ g1a, const float* __restrict__ g1b,
    const float* __restrict__ m1,
    const float* __restrict__ lr_w2,  const float* __restrict__ lr_b2,
    const float* __restrict__ lrh_w2, const float* __restrict__ lrh_b2,
    const float* __restrict__ mix_w2, const float* __restrict__ mix_b2,
    const float* __restrict__ rvi, const float* __restrict__ readv,
    const float* __restrict__ read_h,
    float* __restrict__ hist, float* __restrict__ wts,
    short* __restrict__ ctx_h, short* __restrict__ ctx_l)
{
    const int b = blockIdx.x, t = threadIdx.x;
    const int lane = t & 63, w = t >> 6;
    __shared__ float red[4][5];
    __shared__ float sc[5];

    float pa = 0.f, pb = 0.f, p0 = 0.f, p1 = 0.f, p2 = 0.f;
    for (int k = t; k < 2 * ND; k += 256) {
        pa += g1a[(size_t)b * 2 * ND + k] * lr_w2[k];
        pb += g1b[(size_t)b * 2 * ND + k] * lrh_w2[k];
    }
    for (int d = t; d < ND; d += 256) {
        const float m = m1[(size_t)b * ND + d];
        p0 += m * mix_w2[d];
        p1 += m * mix_w2[ND + d];
        p2 += m * mix_w2[2 * ND + d];
    }
    #pragma unroll
    for (int o = 32; o; o >>= 1) {
        pa += __shfl_down(pa, o); pb += __shfl_down(pb, o);
        p0 += __shfl_down(p0, o); p1 += __shfl_down(p1, o); p2 += __shfl_down(p2, o);
    }
    if (lane == 0) { red[w][0] = pa; red[w][1] = pb; red[w][2] = p0; red[w][3] = p1; red[w][4] = p2; }
    __syncthreads();
    if (t == 0) {
        float sa = 0.f, sb = 0.f, s0 = 0.f, s1 = 0.f, s2 = 0.f;
        #pragma unroll
        for (int i = 0; i < 4; ++i) { sa += red[i][0]; sb += red[i][1]; s0 += red[i][2]; s1 += red[i][3]; s2 += red[i][4]; }
        sc[0] = 1.f / (1.f + expf(-(sa + lr_b2[0])));
        sc[1] = 1.f / (1.f + expf(-(sb + lrh_b2[0])));
        const float l0 = s0 + mix_b2[0], l1 = s1 + mix_b2[1], l2 = s2 + mix_b2[2];
        const float mx = fmaxf(l0, fmaxf(l1, l2));
        const float e0 = expf(l0 - mx), e1 = expf(l1 - mx), e2 = expf(l2 - mx);
        const float inv = 1.f / (e0 + e1 + e2);
        sc[2] = e0 * inv; sc[3] = e1 * inv; sc[4] = e2 * inv;
    }
    __syncthreads();

    const float gk = sc[0], gm = sc[1];
    const float c0 = sc[2], c1 = sc[3], c2 = sc[4];
    __shared__ float wo[NK], Ws[NK];
    if (t < NK) {
        const float w_old = wts[(size_t)b * NK + t];
        wo[t] = w_old;
        Ws[t] = (gm * rvi[(size_t)b * NK + t] + w_old * (1.f - gm)) * gk;
    }
    __syncthreads();
    float Wr[NK];
    #pragma unroll
    for (int k = 0; k < NK; ++k) Wr[k] = Ws[k];

    for (int dd = t; dd < ND; dd += 256) {
        const float rd = readv[(size_t)b * ND + dd];
        const float rh = read_h[(size_t)b * ND + dd];
        const float now = gk * rd, last = gm * rh;
        const float latest = (1.f - gk) * last + now;
        const float cr = c0 * now + c1 * last + c2 * latest;
        short h2, l2; splitbf(cr, h2, l2);
        ctx_h[(size_t)b * ND + dd] = h2;
        ctx_l[(size_t)b * ND + dd] = l2;
        float* hp = hist + (size_t)b * ND * NK + (size_t)dd * NK;
        float4 h0 = *(const float4*)&hp[0];
        float4 h1 = *(const float4*)&hp[4];
        h0.x = h0.x * (1.f - Wr[0]) + rd * Wr[0];
        h0.y = h0.y * (1.f - Wr[1]) + rd * Wr[1];
        h0.z = h0.z * (1.f - Wr[2]) + rd * Wr[2];
        h0.w = h0.w * (1.f - Wr[3]) + rd * Wr[3];
        h1.x = h1.x * (1.f - Wr[4]) + rd * Wr[4];
        h1.y = h1.y * (1.f - Wr[5]) + rd * Wr[5];
        h1.z = h1.z * (1.f - Wr[6]) + rd * Wr[6];
        h1.w = h1.w * (1.f - Wr[7]) + rd * Wr[7];
        *(float4*)&hp[0] = h0;
        *(float4*)&hp[4] = h1;
    }
    if (t == 0) {
        const float first = (1.f - gm) * gk;
        float nw[NK];
        #pragma unroll
        for (int k = 0; k < NK; ++k) nw[k] = wo[(k + 1) & 7] * first + wo[k] * (1.f - first);
        #pragma unroll
        for (int k = 0; k < NK; ++k) wts[(size_t)b * NK + k] = nw[k];
    }
}

// =====================================================================
extern "C" void kernel_launch(void* const* d_in, const int* in_sizes, int n_in,
                              void* d_out, int out_size, void* d_ws, size_t ws_size,
                              hipStream_t stream)
{
    (void)in_sizes; (void)n_in; (void)out_size; (void)ws_size;
    const float* context    = (const float*)d_in[0];
    const float* question   = (const float*)d_in[1];
    const float* knowledge  = (const float*)d_in[2];
    const float* kb_proj    = (const float*)d_in[3];
    const float* control0   = (const float*)d_in[4];
    const float* memory0    = (const float*)d_in[5];
    const float* history0   = (const float*)d_in[6];
    const float* wt0        = (const float*)d_in[7];
    const float* ctrl_pos_w = (const float*)d_in[8];
    const float* ctrl_pos_b = (const float*)d_in[9];
    const float* ctrl_cq_w  = (const float*)d_in[10];
    const float* ctrl_cq_b  = (const float*)d_in[11];
    const float* ctrl_attn_w= (const float*)d_in[12];
    const float* read_mem_w = (const float*)d_in[14];
    const float* read_mem_b = (const float*)d_in[15];
    const float* read_cat_w = (const float*)d_in[16];
    const float* read_attn_w= (const float*)d_in[18];
    const float* rm_mem_w   = (const float*)d_in[20];
    const float* rm_mem_b   = (const float*)d_in[21];
    const float* rm_cat_w   = (const float*)d_in[22];
    const float* rm_attn_w  = (const float*)d_in[24];
    const float* write_w    = (const float*)d_in[26];
    const float* write_b    = (const float*)d_in[27];
    const float* lr_w1      = (const float*)d_in[28];
    const float* lr_b1      = (const float*)d_in[29];
    const float* lr_w2      = (const float*)d_in[30];
    const float* lr_b2      = (const float*)d_in[31];
    const float* lrh_w1     = (const float*)d_in[32];
    const float* lrh_b1     = (const float*)d_in[33];
    const float* lrh_w2     = (const float*)d_in[34];
    const float* lrh_b2     = (const float*)d_in[35];
    const float* mix_w1     = (const float*)d_in[36];
    const float* mix_b1     = (const float*)d_in[37];
    const float* mix_w2     = (const float*)d_in[38];
    const float* mix_b2     = (const float*)d_in[39];

    // ---- workspace (R5 layout) ----
    float* f = (float*)d_ws;
    auto takef = [&](size_t n) { float* p = f; f += n; return p; };
    float* cqi    = takef((size_t)NB * ND);
    float* mpc    = takef((size_t)NB * 1024);
    float* u      = takef((size_t)NB * 1024);
    float* uh     = takef((size_t)NB * 1024);
    float* readv  = takef((size_t)NB * ND);
    float* read_h = takef((size_t)NB * ND);
    float* rvi    = takef((size_t)NB * NK);
    float* g1a    = takef((size_t)NB * 1024);
    float* g1b    = takef((size_t)NB * 1024);
    float* m1buf  = takef((size_t)NB * ND);
    float* hist   = takef((size_t)NB * ND * NK);
    float* wts    = takef((size_t)NB * NK);
    float* s_part = takef((size_t)4 * NB * 200);
    float* bcat   = takef(1024);

    uintptr_t fa = ((uintptr_t)f + 15) & ~(uintptr_t)15;
    short* s = (short*)fa;
    auto takes = [&](size_t n) { short* p = s; s += n; return p; };
    short* cpw_h = takes((size_t)2048 * 1024); short* cpw_l = takes((size_t)2048 * 1024);
    short* cqw_h = takes((size_t)512 * 1024);  short* cqw_l = takes((size_t)512 * 1024);
    short* wmc_h = takes((size_t)1024 * 512);  short* wmc_l = takes((size_t)1024 * 512);
    short* rcw_h = takes((size_t)1024 * 512);  short* rcw_l = takes((size_t)1024 * 512);
    short* rmw_h = takes((size_t)1024 * 512);  short* rmw_l = takes((size_t)1024 * 512);
    short* lrw_h = takes((size_t)1024 * 1024); short* lrw_l = takes((size_t)1024 * 1024);
    short* lhw_h = takes((size_t)1024 * 1024); short* lhw_l = takes((size_t)1024 * 1024);
    short* mxw_h = takes((size_t)512 * 512);   short* mxw_l = takes((size_t)512 * 512);
    short* ww_h  = takes((size_t)512 * 1024);  short* ww_l  = takes((size_t)512 * 1024);
    short* q_h   = takes((size_t)512 * 1024);  short* q_l   = takes((size_t)512 * 1024);
    short* c0_h  = takes((size_t)NB * ND);     short* c0_l  = takes((size_t)NB * ND);
    short* m0_h  = takes((size_t)NB * ND);     short* m0_l  = takes((size_t)NB * ND);
    short* pa_h  = takes((size_t)NB * 2048);   short* pa_l  = takes((size_t)NB * 2048);
    short* ct_h  = takes((size_t)NB * ND);     short* ct_l  = takes((size_t)NB * ND);
    short* cw_h  = takes((size_t)NB * ND);     short* cw_l  = takes((size_t)NB * ND);
    short* cwh_h = takes((size_t)NB * ND);     short* cwh_l = takes((size_t)NB * ND);
    short* rv_h  = takes((size_t)NB * ND);     short* rv_l  = takes((size_t)NB * ND);
    short* rh_h  = takes((size_t)NB * ND);     short* rh_l  = takes((size_t)NB * ND);
    short* cx_h  = takes((size_t)NB * ND);     short* cx_l  = takes((size_t)NB * ND);
    short* mA_h  = takes((size_t)NB * ND);     short* mA_l  = takes((size_t)NB * ND);
    short* mB_h  = takes((size_t)NB * ND);     short* mB_l  = takes((size_t)NB * ND);
    short* mC_h  = takes((size_t)NB * ND);     short* mC_l  = takes((size_t)NB * ND);
    unsigned short* kbp_bf = (unsigned short*)s;
    unsigned short* knw_bf = kbp_bf + (size_t)NB * ND * NHW;

    // ---- prologue (R5): state copies + weight conversion ----
    hipMemcpyAsync(hist, history0, sizeof(float) * NB * ND * NK, hipMemcpyDeviceToDevice, stream);
    hipMemcpyAsync(wts,  wt0,      sizeof(float) * NB * NK,      hipMemcpyDeviceToDevice, stream);
    hipMemcpyAsync(bcat,       read_mem_b, sizeof(float) * 512, hipMemcpyDeviceToDevice, stream);
    hipMemcpyAsync(bcat + 512, rm_mem_b,   sizeof(float) * 512, hipMemcpyDeviceToDevice, stream);

    WTab tab;
    tab.s[0]  = {ctrl_pos_w, cpw_h, cpw_l, 2048 * 1024};
    tab.s[1]  = {ctrl_cq_w,  cqw_h, cqw_l, 512 * 1024};
    tab.s[2]  = {read_mem_w, wmc_h, wmc_l, 512 * 512};
    tab.s[3]  = {rm_mem_w,   wmc_h + 512 * 512, wmc_l + 512 * 512, 512 * 512};
    tab.s[4]  = {lr_w1,  lrw_h, lrw_l, 1024 * 1024};
    tab.s[5]  = {lrh_w1, lhw_h, lhw_l, 1024 * 1024};
    tab.s[6]  = {mix_w1, mxw_h, mxw_l, 512 * 512};
    tab.s[7]  = {write_w, ww_h, ww_l, 512 * 1024};
    tab.s[8]  = {question, q_h, q_l, 512 * 1024};
    tab.s[9]  = {control0, c0_h, c0_l, 512 * 512};
    tab.s[10] = {memory0,  m0_h, m0_l, 512 * 512};
    tab.s[11] = {nullptr, nullptr, nullptr, 0};
    tab.total = 2048*1024 + 512*1024 + 512*512 + 512*512 + 1024*1024 + 1024*1024
              + 512*512 + 512*1024 + 512*1024 + 512*512 + 512*512;
    wconv_k<<<dim3((tab.total + 255) / 256), dim3(256), 0, stream>>>(tab);
    tconv_k<<<dim3(32, 16, 2), dim3(256), 0, stream>>>(read_cat_w, rcw_h, rcw_l,
                                                       rm_cat_w,  rmw_h, rmw_l);

    auto P = [](const short* A1h, const short* A1l, int lda1, int k1,
                const short* A2h, const short* A2l, int lda2,
                const short* Bh, const short* Bl, const float* bias,
                float* C, short* Ch, short* Cl, int N, int K, int t0, int act,
                int ldc, int full) {
        GP q; q.A1h = A1h; q.A1l = A1l; q.A2h = A2h; q.A2l = A2l;
        q.Bh = Bh; q.Bl = Bl; q.bias = bias; q.C = C; q.Ch = Ch; q.Cl = Cl;
        q.lda1 = lda1; q.lda2 = lda2; q.k1 = k1; q.N = N; q.K = K;
        q.ntN = N / 64; q.t0 = t0; q.act = act; q.ldc = ldc; q.full = full;
        return q;
    };
    auto tilesOf = [](int N) { return (NB / 32) * (N / 64); };
    auto GG = [&](GPG g, int total) {
        ggemm_k<<<dim3(total), dim3(256), 0, stream>>>(g);
    };

    // pa for all 4 steps (full precision: feeds control chain)
    {
        GPG g; g.np = 1;
        g.p[0] = P(q_h, q_l, 1024, 1024, q_h, q_l, 1024, cpw_h, cpw_l, ctrl_pos_b,
                   nullptr, pa_h, pa_l, 2048, 1024, 0, 0, 2048, 1);
        GG(g, tilesOf(2048));
    }

    const short* mems_h[4] = {m0_h, mA_h, mB_h, mC_h};
    const short* mems_l[4] = {m0_l, mA_l, mB_l, mC_l};
    const short* ctl_h = c0_h;
    const short* ctl_l = c0_l;

    for (int i = 0; i < NSTEP; ++i) {
        // ---- A: {write_{i-1} (if i>0)} + {cqi_i} ----
        {
            GPG g; int nt = 0, np = 0;
            if (i > 0) {
                g.p[np++] = P(cx_h, cx_l, ND, ND, mems_h[i - 1], mems_l[i - 1], ND,
                              ww_h, ww_l, write_b, nullptr,
                              (short*)mems_h[i], (short*)mems_l[i], ND, 1024, nt, 0, ND, 1);
                nt += tilesOf(ND);
            }
            g.p[np++] = P(ctl_h, ctl_l, ND, ND, pa_h + (size_t)i * ND, pa_l + (size_t)i * ND, 2048,
                          cqw_h, cqw_l, ctrl_cq_b, cqi, nullptr, nullptr, ND, 1024, nt, 0, ND, 1);
            nt += tilesOf(ND);
            g.np = np;
            GG(g, nt);
        }
        // ---- B: control attention ----
        ctrl_attn_k<<<dim3(NB), dim3(512), 0, stream>>>(cqi, context, ctrl_attn_w,
                                                        read_attn_w, rm_attn_w,
                                                        ct_h, ct_l, cw_h, cw_l, cwh_h, cwh_l);
        ctl_h = ct_h; ctl_l = ct_l;
        // ---- C: {mpc (full), u (2-pass), uh (2-pass)} ----
        {
            GPG g; g.np = 3;
            g.p[0] = P(mems_h[i], mems_l[i], ND, ND, mems_h[i], mems_l[i], ND,
                       wmc_h, wmc_l, bcat, mpc, nullptr, nullptr, 1024, 512, 0, 0, 1024, 1);
            g.p[1] = P(cw_h, cw_l, ND, ND, cw_h, cw_l, ND,
                       rcw_h, rcw_l, nullptr, u, nullptr, nullptr, 1024, 512, 256, 0, 1024, 0);
            g.p[2] = P(cwh_h, cwh_l, ND, ND, cwh_h, cwh_l, ND,
                       rmw_h, rmw_l, nullptr, uh, nullptr, nullptr, 1024, 512, 512, 0, 1024, 0);
            GG(g, 768);
        }
        // ---- D: kb scores + hist attention ----
        if (i == 0)
            kbsh_k<1><<<dim3(5 * NB), dim3(256), 0, stream>>>(kb_proj, kbp_bf, mpc, u, s_part,
                                                              hist, uh, rvi, read_h, rh_h, rh_l);
        else
            kbsh_k<0><<<dim3(5 * NB), dim3(256), 0, stream>>>(kb_proj, kbp_bf, mpc, u, s_part,
                                                              hist, uh, rvi, read_h, rh_h, rh_l);
        // ---- E: kb softmax + read ----
        if (i == 0)
            kb_read_k<1><<<dim3(8, NB), dim3(256), 0, stream>>>(knowledge, knw_bf, s_part,
                                                                readv, rv_h, rv_l);
        else
            kb_read_k<0><<<dim3(8, NB), dim3(256), 0, stream>>>(knowledge, knw_bf, s_part,
                                                                readv, rv_h, rv_l);
        // ---- F: {g1a, g1b, m1} (ELU; all 2-pass — gate/softmax-bound) ----
        {
            GPG g; g.np = 3;
            g.p[0] = P(ct_h, ct_l, ND, ND, rv_h, rv_l, ND,
                       lrw_h, lrw_l, lr_b1, g1a, nullptr, nullptr, 1024, 1024, 0, 1, 1024, 0);
            g.p[1] = P(ct_h, ct_l, ND, ND, rh_h, rh_l, ND,
                       lhw_h, lhw_l, lrh_b1, g1b, nullptr, nullptr, 1024, 1024, 256, 1, 1024, 0);
            g.p[2] = P(ct_h, ct_l, ND, ND, ct_h, ct_l, ND,
                       mxw_h, mxw_l, mix_b1, m1buf, nullptr, nullptr, 512, 512, 512, 1, 512, 0);
            GG(g, 640);
        }
        // ---- G: scalars + state update ----
        update2_k<<<dim3(NB), dim3(256), 0, stream>>>(g1a, g1b, m1buf,
                                                      lr_w2, lr_b2, lrh_w2, lrh_b2,
                                                      mix_w2, mix_b2, rvi, readv, read_h,
                                                      hist, wts, cx_h, cx_l);
    }
    // ---- final write -> d_out (full precision) ----
    {
        GPG g; g.np = 1;
        g.p[0] = P(cx_h, cx_l, ND, ND, mems_h[3], mems_l[3], ND,
                   ww_h, ww_l, write_b, (float*)d_out, nullptr, nullptr, ND, 1024, 0, 0, ND, 1);
        GG(g, tilesOf(ND));
    }
}

// Round 10
// 1052.600 us; speedup vs baseline: 1.0105x; 1.0105x over previous
//
#include <hip/hip_runtime.h>
#include <cstddef>

constexpr int NB   = 512;  // batch
constexpr int ND   = 512;  // dim
constexpr int NL   = 32;   // context length
constexpr int NHW  = 196;  // knowledge spatial
constexpr int NK   = 8;    // history slots
constexpr int NSTEP = 4;

typedef __attribute__((ext_vector_type(8))) short short8v;
typedef __attribute__((ext_vector_type(4))) float f32x4;

__device__ __forceinline__ void splitbf(float x, short& h, short& l) {
    unsigned u  = __float_as_uint(x);
    unsigned hb = (u + 0x7FFFu + ((u >> 16) & 1u)) & 0xFFFF0000u;
    h = (short)(hb >> 16);
    float rem = x - __uint_as_float(hb);
    unsigned v = __float_as_uint(rem);
    l = (short)((v + 0x7FFFu + ((v >> 16) & 1u)) >> 16);
}
__device__ __forceinline__ unsigned short f2bf(float x) {
    unsigned u = __float_as_uint(x);
    return (unsigned short)((u + 0x7FFFu + ((u >> 16) & 1u)) >> 16);
}
__device__ __forceinline__ float bf2f(unsigned short h) {
    return __uint_as_float(((unsigned)h) << 16);
}

// =====================================================================
// LDS-staged grouped split-bf16 MFMA GEMM (R5 K-loop, BK=32, 3-pass).
//  C = act(concat(A1,A2) @ Bw^T + bias); A,B pre-split bf16 hi/lo planes.
//  act is a runtime field used ONLY in the epilogue (hot loop = R5 exact).
//  Up to 5 problems per launch. LDS rows padded to 40 shorts.
// =====================================================================
struct GP {
    const short *A1h, *A1l, *A2h, *A2l, *Bh, *Bl;
    const float* bias;
    float* C; short* Ch; short* Cl;
    int lda1, lda2, k1, N, K, ntN, t0, act;
};
struct GPG { GP p[5]; int np; };

__device__ void dev_gemm(const GP& p, int local, int t, char* smem)
{
    short (*Ah)[40]   = (short(*)[40])(smem);
    short (*Al)[40]   = (short(*)[40])(smem + 2560);
    short (*Bh_s)[40] = (short(*)[40])(smem + 5120);
    short (*Bl_s)[40] = (short(*)[40])(smem + 10240);
    const int my = local / p.ntN, nx = local - my * p.ntN;
    const int m0 = my * 32, n0 = nx * 64;
    const int lane = t & 63, wid = t >> 6;
    const int wr = wid >> 1, wc = wid & 1;
    const int lr = lane & 15, lk = (lane >> 4) * 8;
    const int ar = (t & 127) >> 2, ak = (t & 3) * 8;
    const bool alo = t >= 128;
    const int br = t >> 2, bk = (t & 3) * 8;

    f32x4 acc0 = {}, acc1 = {};
    for (int kt = 0; kt < p.K; kt += 32) {
        {
            const int gk = kt + ak;
            const short* srcp = (gk < p.k1)
                ? (alo ? p.A1l : p.A1h) + (size_t)(m0 + ar) * p.lda1 + gk
                : (alo ? p.A2l : p.A2h) + (size_t)(m0 + ar) * p.lda2 + (gk - p.k1);
            short8v v = *(const short8v*)srcp;
            if (alo) *(short8v*)&Al[ar][ak] = v;
            else     *(short8v*)&Ah[ar][ak] = v;
        }
        {
            const size_t off = (size_t)(n0 + br) * p.K + kt + bk;
            *(short8v*)&Bh_s[br][bk] = *(const short8v*)(p.Bh + off);
            *(short8v*)&Bl_s[br][bk] = *(const short8v*)(p.Bl + off);
        }
        __syncthreads();
        short8v ah  = *(short8v*)&Ah[wr * 16 + lr][lk];
        short8v al  = *(short8v*)&Al[wr * 16 + lr][lk];
        short8v bh0 = *(short8v*)&Bh_s[wc * 32      + lr][lk];
        short8v bh1 = *(short8v*)&Bh_s[wc * 32 + 16 + lr][lk];
        short8v bl0 = *(short8v*)&Bl_s[wc * 32      + lr][lk];
        short8v bl1 = *(short8v*)&Bl_s[wc * 32 + 16 + lr][lk];
        acc0 = __builtin_amdgcn_mfma_f32_16x16x32_bf16(ah, bh0, acc0, 0, 0, 0);
        acc1 = __builtin_amdgcn_mfma_f32_16x16x32_bf16(ah, bh1, acc1, 0, 0, 0);
        acc0 = __builtin_amdgcn_mfma_f32_16x16x32_bf16(al, bh0, acc0, 0, 0, 0);
        acc1 = __builtin_amdgcn_mfma_f32_16x16x32_bf16(al, bh1, acc1, 0, 0, 0);
        acc0 = __builtin_amdgcn_mfma_f32_16x16x32_bf16(ah, bl0, acc0, 0, 0, 0);
        acc1 = __builtin_amdgcn_mfma_f32_16x16x32_bf16(ah, bl1, acc1, 0, 0, 0);
        __syncthreads();
    }
    const int r0 = m0 + wr * 16 + ((lane >> 4) << 2);
    const int cb = n0 + wc * 32 + lr;
    #pragma unroll
    for (int fc = 0; fc < 2; ++fc) {
        const f32x4& a = fc ? acc1 : acc0;
        const int col = cb + fc * 16;
        const float badd = p.bias ? p.bias[col] : 0.f;
        #pragma unroll
        for (int rr = 0; rr < 4; ++rr) {
            float x = a[rr] + badd;
            if (p.act) x = (x > 0.f) ? x : (expf(x) - 1.f);
            const size_t idx = (size_t)(r0 + rr) * p.N + col;
            if (p.C) p.C[idx] = x;
            if (p.Ch) { short h, l; splitbf(x, h, l); p.Ch[idx] = h; p.Cl[idx] = l; }
        }
    }
}

__global__ __launch_bounds__(256) void ggemm_k(GPG g)
{
    __shared__ __align__(16) char smem[15360];
    const int bid = blockIdx.x;
    int pi = 0;
    #pragma unroll
    for (int j = 1; j < 5; ++j)
        if (j < g.np && bid >= g.p[j].t0) pi = j;
    dev_gemm(g.p[pi], bid - g.p[pi].t0, threadIdx.x, smem);
}

// =====================================================================
// Weight/activation conversion prologue (R5): fp32 -> bf16 hi/lo
// =====================================================================
struct WSeg { const float* src; short* dh; short* dl; int n; };
struct WTab { WSeg s[12]; int total; };

__global__ __launch_bounds__(256) void wconv_k(WTab tab)
{
    int i = blockIdx.x * 256 + threadIdx.x;
    if (i >= tab.total) return;
    int seg = 0, off = i;
    while (off >= tab.s[seg].n) { off -= tab.s[seg].n; ++seg; }
    short h, l; splitbf(tab.s[seg].src[off], h, l);
    tab.s[seg].dh[off] = h;
    tab.s[seg].dl[off] = l;
}

// Transpose-convert with per-k row scaling (folds attn weight into matrix):
//  dst[n][k] = src[k][n] * wv[k]
__global__ __launch_bounds__(256) void tconv_k(
    const float* s0, const float* w0, short* dh0, short* dl0,
    const float* s1, const float* w1, short* dh1, short* dl1)
{
    const float* src = blockIdx.z ? s1 : s0;
    const float* wv  = blockIdx.z ? w1 : w0;
    short* dh = blockIdx.z ? dh1 : dh0;
    short* dl = blockIdx.z ? dl1 : dl0;
    __shared__ float tile[32][33];
    const int n0 = blockIdx.x * 32, k0 = blockIdx.y * 32;
    const int tx = threadIdx.x & 31, ty = threadIdx.x >> 5;
    for (int i = ty; i < 32; i += 8)
        tile[i][tx] = src[(size_t)(k0 + i) * 1024 + n0 + tx];
    __syncthreads();
    const float wk = wv[k0 + tx];
    for (int i = ty; i < 32; i += 8) {
        short h, l; splitbf(tile[tx][i] * wk, h, l);
        dh[(size_t)(n0 + i) * 512 + k0 + tx] = h;
        dl[(size_t)(n0 + i) * 512 + k0 + tx] = l;
    }
}

// =====================================================================
// Control attention: emits only control hi/lo planes (attn weights are
// folded into rcw/rmw). 512 threads, one block per batch element.
// =====================================================================
__global__ __launch_bounds__(512) void ctrl_attn_k(
    const float* __restrict__ cqi, const float* __restrict__ context,
    const float* __restrict__ attn_w,
    short* __restrict__ ct_h, short* __restrict__ ct_l)
{
    const int b = blockIdx.x, t = threadIdx.x;
    const int lane = t & 63, w = t >> 6;
    __shared__ float q[ND];
    __shared__ float p[NL];
    const float* ctx = context + (size_t)b * NL * ND;

    q[t] = cqi[(size_t)b * ND + t] * attn_w[t];
    __syncthreads();

    for (int l = w; l < NL; l += 8) {
        float s = 0.f;
        const float* row = ctx + (size_t)l * ND;
        #pragma unroll
        for (int d = lane; d < ND; d += 64) s += q[d] * row[d];
        #pragma unroll
        for (int o = 32; o; o >>= 1) s += __shfl_down(s, o);
        if (lane == 0) p[l] = s;
    }
    __syncthreads();
    if (t == 0) {
        float mx = p[0];
        for (int l = 1; l < NL; ++l) mx = fmaxf(mx, p[l]);
        float sum = 0.f;
        for (int l = 0; l < NL; ++l) { float e = expf(p[l] - mx); p[l] = e; sum += e; }
        const float inv = 1.f / sum;
        for (int l = 0; l < NL; ++l) p[l] *= inv;
    }
    __syncthreads();
    float a = 0.f;
    #pragma unroll 8
    for (int l = 0; l < NL; ++l) a += p[l] * ctx[(size_t)l * ND + t];
    const size_t ix = (size_t)b * ND + t;
    short h, l2;
    splitbf(a, h, l2);
    ct_h[ix] = h; ct_l[ix] = l2;
}

// =====================================================================
// Merged kb_score + hist_attn (R5).
// =====================================================================
template<int FIRST>
__global__ __launch_bounds__(256) void kbsh_k(
    const float* __restrict__ kbp_f32, unsigned short* __restrict__ kbp_bf,
    const float* __restrict__ mpc, const float* __restrict__ u,
    float* __restrict__ s_part,
    const float* __restrict__ hist, const float* __restrict__ uh,
    float* __restrict__ rvi, float* __restrict__ read_h,
    short* __restrict__ rh_h, short* __restrict__ rh_l)
{
    __shared__ float sh[NK * ND + ND];
    __shared__ float sred[NK], pk[NK];
    const int bx = blockIdx.x, t = threadIdx.x;
    const int lane = t & 63, w = t >> 6;

    if (bx < 4 * NB) {
        const int jc = bx >> 9, b = bx & 511;
        float* v = sh;
        const int j0 = jc * 128;
        if (t < 128) {
            const int j = j0 + t;
            v[t] = mpc[(size_t)b * 1024 + j] * u[(size_t)b * 1024 + j]
                 + u[(size_t)b * 1024 + 512 + j];
        }
        __syncthreads();
        if (t < NHW) {
            const size_t base = (size_t)b * ND * NHW + (size_t)j0 * NHW + t;
            float s = 0.f;
            #pragma unroll 4
            for (int j = 0; j < 128; ++j) {
                float x;
                if (FIRST) {
                    x = kbp_f32[base + (size_t)j * NHW];
                    kbp_bf[base + (size_t)j * NHW] = f2bf(x);
                } else {
                    x = bf2f(kbp_bf[base + (size_t)j * NHW]);
                }
                s += x * v[j];
            }
            s_part[((size_t)jc * NB + b) * 200 + t] = s;
        }
    } else {
        const int b = bx - 4 * NB;
        float* ht = sh;
        float* vh = sh + NK * ND;
        const float* hb = hist + (size_t)b * ND * NK;

        for (int dd = t; dd < ND; dd += 256) {
            float4 h0 = *(const float4*)&hb[(size_t)dd * NK];
            float4 h1 = *(const float4*)&hb[(size_t)dd * NK + 4];
            ht[0 * ND + dd] = h0.x; ht[1 * ND + dd] = h0.y;
            ht[2 * ND + dd] = h0.z; ht[3 * ND + dd] = h0.w;
            ht[4 * ND + dd] = h1.x; ht[5 * ND + dd] = h1.y;
            ht[6 * ND + dd] = h1.z; ht[7 * ND + dd] = h1.w;
            vh[dd] = mpc[(size_t)b * 1024 + 512 + dd] * uh[(size_t)b * 1024 + dd]
                   + uh[(size_t)b * 1024 + 512 + dd];
        }
        __syncthreads();

        for (int k = w; k < NK; k += 4) {
            float s = 0.f;
            #pragma unroll 4
            for (int dd = lane; dd < ND; dd += 64) s += ht[k * ND + dd] * vh[dd];
            #pragma unroll
            for (int o = 32; o; o >>= 1) s += __shfl_down(s, o);
            if (lane == 0) sred[k] = s;
        }
        __syncthreads();
        if (t == 0) {
            float mx = sred[0];
            #pragma unroll
            for (int k = 1; k < NK; ++k) mx = fmaxf(mx, sred[k]);
            float ev[NK]; float sum = 0.f;
            #pragma unroll
            for (int k = 0; k < NK; ++k) { ev[k] = expf(sred[k] - mx); sum += ev[k]; }
            const float inv = 1.f / sum;
            #pragma unroll
            for (int k = 0; k < NK; ++k) { float pv = ev[k] * inv; pk[k] = pv; rvi[(size_t)b * NK + k] = pv; }
        }
        __syncthreads();
        for (int dd = t; dd < ND; dd += 256) {
            float a = 0.f;
            #pragma unroll
            for (int k = 0; k < NK; ++k) a += pk[k] * ht[k * ND + dd];
            const size_t ix = (size_t)b * ND + dd;
            read_h[ix] = a;
            short h, l; splitbf(a, h, l);
            rh_h[ix] = h; rh_l[ix] = l;
        }
    }
}

// =====================================================================
// KB read (R5).
// =====================================================================
template<int FIRST>
__global__ __launch_bounds__(256) void kb_read_k(
    const float* __restrict__ knw_f32, unsigned short* __restrict__ knw_bf,
    const float* __restrict__ s_part,
    float* __restrict__ readv, short* __restrict__ rv_h, short* __restrict__ rv_l)
{
    const int dcb = blockIdx.x, b = blockIdx.y, t = threadIdx.x;
    const int lane = t & 63, w = t >> 6;
    __shared__ float ps[200];
    __shared__ float red[8];

    float val = -INFINITY;
    if (t < NHW) {
        float sp = 0.f;
        #pragma unroll
        for (int jc = 0; jc < 4; ++jc) sp += s_part[((size_t)jc * NB + b) * 200 + t];
        val = sp;
    }
    float mx = val;
    #pragma unroll
    for (int o = 32; o; o >>= 1) mx = fmaxf(mx, __shfl_xor(mx, o));
    if (lane == 0) red[w] = mx;
    __syncthreads();
    mx = fmaxf(fmaxf(red[0], red[1]), fmaxf(red[2], red[3]));
    const float e = (t < NHW) ? expf(val - mx) : 0.f;
    float sm = e;
    #pragma unroll
    for (int o = 32; o; o >>= 1) sm += __shfl_xor(sm, o);
    if (lane == 0) red[4 + w] = sm;
    __syncthreads();
    const float tot = red[4] + red[5] + red[6] + red[7];
    if (t < 200) ps[t] = (t < NHW) ? e / tot : 0.f;
    __syncthreads();

    const int d1 = dcb * 64 + 64;
    for (int d = dcb * 64 + w; d < d1; d += 4) {
        const size_t rbase = (size_t)b * ND * NHW + (size_t)d * NHW;
        float a = 0.f;
        for (int h = lane; h < NHW; h += 64) {
            float x;
            if (FIRST) {
                x = knw_f32[rbase + h];
                knw_bf[rbase + h] = f2bf(x);
            } else {
                x = bf2f(knw_bf[rbase + h]);
            }
            a += ps[h] * x;
        }
        #pragma unroll
        for (int o = 32; o; o >>= 1) a += __shfl_down(a, o);
        if (lane == 0) {
            const size_t ix = (size_t)b * ND + d;
            readv[ix] = a;
            short h2, l2; splitbf(a, h2, l2);
            rv_h[ix] = h2; rv_l[ix] = l2;
        }
    }
}

// =====================================================================
// Merged scalars + state update (R5).
// =====================================================================
__global__ __launch_bounds__(256) void update2_k(
    const float* __restrict__ g1a, const float* __restrict__ g1b,
    const float* __restrict__ m1,
    const float* __restrict__ lr_w2,  const float* __restrict__ lr_b2,
    const float* __restrict__ lrh_w2, const float* __restrict__ lrh_b2,
    const float* __restrict__ mix_w2, const float* __restrict__ mix_b2,
    const float* __restrict__ rvi, const float* __restrict__ readv,
    const float* __restrict__ read_h,
    float* __restrict__ hist, float* __restrict__ wts,
    short* __restrict__ ctx_h, short* __restrict__ ctx_l)
{
    const int b = blockIdx.x, t = threadIdx.x;
    const int lane = t & 63, w = t >> 6;
    __shared__ float red[4][5];
    __shared__ float sc[5];

    float pa = 0.f, pb = 0.f, p0 = 0.f, p1 = 0.f, p2 = 0.f;
    for (int k = t; k < 2 * ND; k += 256) {
        pa += g1a[(size_t)b * 2 * ND + k] * lr_w2[k];
        pb += g1b[(size_t)b * 2 * ND + k] * lrh_w2[k];
    }
    for (int d = t; d < ND; d += 256) {
        const float m = m1[(size_t)b * ND + d];
        p0 += m * mix_w2[d];
        p1 += m * mix_w2[ND + d];
        p2 += m * mix_w2[2 * ND + d];
    }
    #pragma unroll
    for (int o = 32; o; o >>= 1) {
        pa += __shfl_down(pa, o); pb += __shfl_down(pb, o);
        p0 += __shfl_down(p0, o); p1 += __shfl_down(p1, o); p2 += __shfl_down(p2, o);
    }
    if (lane == 0) { red[w][0] = pa; red[w][1] = pb; red[w][2] = p0; red[w][3] = p1; red[w][4] = p2; }
    __syncthreads();
    if (t == 0) {
        float sa = 0.f, sb = 0.f, s0 = 0.f, s1 = 0.f, s2 = 0.f;
        #pragma unroll
        for (int i = 0; i < 4; ++i) { sa += red[i][0]; sb += red[i][1]; s0 += red[i][2]; s1 += red[i][3]; s2 += red[i][4]; }
        sc[0] = 1.f / (1.f + expf(-(sa + lr_b2[0])));
        sc[1] = 1.f / (1.f + expf(-(sb + lrh_b2[0])));
        const float l0 = s0 + mix_b2[0], l1 = s1 + mix_b2[1], l2 = s2 + mix_b2[2];
        const float mx = fmaxf(l0, fmaxf(l1, l2));
        const float e0 = expf(l0 - mx), e1 = expf(l1 - mx), e2 = expf(l2 - mx);
        const float inv = 1.f / (e0 + e1 + e2);
        sc[2] = e0 * inv; sc[3] = e1 * inv; sc[4] = e2 * inv;
    }
    __syncthreads();

    const float gk = sc[0], gm = sc[1];
    const float c0 = sc[2], c1 = sc[3], c2 = sc[4];
    __shared__ float wo[NK], Ws[NK];
    if (t < NK) {
        const float w_old = wts[(size_t)b * NK + t];
        wo[t] = w_old;
        Ws[t] = (gm * rvi[(size_t)b * NK + t] + w_old * (1.f - gm)) * gk;
    }
    __syncthreads();
    float Wr[NK];
    #pragma unroll
    for (int k = 0; k < NK; ++k) Wr[k] = Ws[k];

    for (int dd = t; dd < ND; dd += 256) {
        const float rd = readv[(size_t)b * ND + dd];
        const float rh = read_h[(size_t)b * ND + dd];
        const float now = gk * rd, last = gm * rh;
        const float latest = (1.f - gk) * last + now;
        const float cr = c0 * now + c1 * last + c2 * latest;
        short h2, l2; splitbf(cr, h2, l2);
        ctx_h[(size_t)b * ND + dd] = h2;
        ctx_l[(size_t)b * ND + dd] = l2;
        float* hp = hist + (size_t)b * ND * NK + (size_t)dd * NK;
        float4 h0 = *(const float4*)&hp[0];
        float4 h1 = *(const float4*)&hp[4];
        h0.x = h0.x * (1.f - Wr[0]) + rd * Wr[0];
        h0.y = h0.y * (1.f - Wr[1]) + rd * Wr[1];
        h0.z = h0.z * (1.f - Wr[2]) + rd * Wr[2];
        h0.w = h0.w * (1.f - Wr[3]) + rd * Wr[3];
        h1.x = h1.x * (1.f - Wr[4]) + rd * Wr[4];
        h1.y = h1.y * (1.f - Wr[5]) + rd * Wr[5];
        h1.z = h1.z * (1.f - Wr[6]) + rd * Wr[6];
        h1.w = h1.w * (1.f - Wr[7]) + rd * Wr[7];
        *(float4*)&hp[0] = h0;
        *(float4*)&hp[4] = h1;
    }
    if (t == 0) {
        const float first = (1.f - gm) * gk;
        float nw[NK];
        #pragma unroll
        for (int k = 0; k < NK; ++k) nw[k] = wo[(k + 1) & 7] * first + wo[k] * (1.f - first);
        #pragma unroll
        for (int k = 0; k < NK; ++k) wts[(size_t)b * NK + k] = nw[k];
    }
}

// =====================================================================
extern "C" void kernel_launch(void* const* d_in, const int* in_sizes, int n_in,
                              void* d_out, int out_size, void* d_ws, size_t ws_size,
                              hipStream_t stream)
{
    (void)in_sizes; (void)n_in; (void)out_size; (void)ws_size;
    const float* context    = (const float*)d_in[0];
    const float* question   = (const float*)d_in[1];
    const float* knowledge  = (const float*)d_in[2];
    const float* kb_proj    = (const float*)d_in[3];
    const float* control0   = (const float*)d_in[4];
    const float* memory0    = (const float*)d_in[5];
    const float* history0   = (const float*)d_in[6];
    const float* wt0        = (const float*)d_in[7];
    const float* ctrl_pos_w = (const float*)d_in[8];
    const float* ctrl_pos_b = (const float*)d_in[9];
    const float* ctrl_cq_w  = (const float*)d_in[10];
    const float* ctrl_cq_b  = (const float*)d_in[11];
    const float* ctrl_attn_w= (const float*)d_in[12];
    const float* read_mem_w = (const float*)d_in[14];
    const float* read_mem_b = (const float*)d_in[15];
    const float* read_cat_w = (const float*)d_in[16];
    const float* read_attn_w= (const float*)d_in[18];
    const float* rm_mem_w   = (const float*)d_in[20];
    const float* rm_mem_b   = (const float*)d_in[21];
    const float* rm_cat_w   = (const float*)d_in[22];
    const float* rm_attn_w  = (const float*)d_in[24];
    const float* write_w    = (const float*)d_in[26];
    const float* write_b    = (const float*)d_in[27];
    const float* lr_w1      = (const float*)d_in[28];
    const float* lr_b1      = (const float*)d_in[29];
    const float* lr_w2      = (const float*)d_in[30];
    const float* lr_b2      = (const float*)d_in[31];
    const float* lrh_w1     = (const float*)d_in[32];
    const float* lrh_b1     = (const float*)d_in[33];
    const float* lrh_w2     = (const float*)d_in[34];
    const float* lrh_b2     = (const float*)d_in[35];
    const float* mix_w1     = (const float*)d_in[36];
    const float* mix_b1     = (const float*)d_in[37];
    const float* mix_w2     = (const float*)d_in[38];
    const float* mix_b2     = (const float*)d_in[39];

    // ---- workspace ----
    float* f = (float*)d_ws;
    auto takef = [&](size_t n) { float* p = f; f += n; return p; };
    float* cqi    = takef((size_t)NB * ND);
    float* mpc    = takef((size_t)NB * 1024);
    float* u      = takef((size_t)NB * 1024);
    float* uh     = takef((size_t)NB * 1024);
    float* readv  = takef((size_t)NB * ND);
    float* read_h = takef((size_t)NB * ND);
    float* rvi    = takef((size_t)NB * NK);
    float* g1a    = takef((size_t)NB * 1024);
    float* g1b    = takef((size_t)NB * 1024);
    float* m1buf  = takef((size_t)NB * ND);
    float* hist   = takef((size_t)NB * ND * NK);
    float* wts    = takef((size_t)NB * NK);
    float* s_part = takef((size_t)4 * NB * 200);
    float* bcat   = takef(1024);

    uintptr_t fa = ((uintptr_t)f + 15) & ~(uintptr_t)15;
    short* s = (short*)fa;
    auto takes = [&](size_t n) { short* p = s; s += n; return p; };
    short* cpw_h = takes((size_t)2048 * 1024); short* cpw_l = takes((size_t)2048 * 1024);
    short* cqw_h = takes((size_t)512 * 1024);  short* cqw_l = takes((size_t)512 * 1024);
    short* wmc_h = takes((size_t)1024 * 512);  short* wmc_l = takes((size_t)1024 * 512);
    short* rcw_h = takes((size_t)1024 * 512);  short* rcw_l = takes((size_t)1024 * 512);
    short* rmw_h = takes((size_t)1024 * 512);  short* rmw_l = takes((size_t)1024 * 512);
    short* lrw_h = takes((size_t)1024 * 1024); short* lrw_l = takes((size_t)1024 * 1024);
    short* lhw_h = takes((size_t)1024 * 1024); short* lhw_l = takes((size_t)1024 * 1024);
    short* mxw_h = takes((size_t)512 * 512);   short* mxw_l = takes((size_t)512 * 512);
    short* ww_h  = takes((size_t)512 * 1024);  short* ww_l  = takes((size_t)512 * 1024);
    short* q_h   = takes((size_t)512 * 1024);  short* q_l   = takes((size_t)512 * 1024);
    short* c0_h  = takes((size_t)NB * ND);     short* c0_l  = takes((size_t)NB * ND);
    short* m0_h  = takes((size_t)NB * ND);     short* m0_l  = takes((size_t)NB * ND);
    short* pa_h  = takes((size_t)NB * 2048);   short* pa_l  = takes((size_t)NB * 2048);
    short* ct_h  = takes((size_t)NB * ND);     short* ct_l  = takes((size_t)NB * ND);
    short* rv_h  = takes((size_t)NB * ND);     short* rv_l  = takes((size_t)NB * ND);
    short* rh_h  = takes((size_t)NB * ND);     short* rh_l  = takes((size_t)NB * ND);
    short* cx_h  = takes((size_t)NB * ND);     short* cx_l  = takes((size_t)NB * ND);
    short* mA_h  = takes((size_t)NB * ND);     short* mA_l  = takes((size_t)NB * ND);
    short* mB_h  = takes((size_t)NB * ND);     short* mB_l  = takes((size_t)NB * ND);
    short* mC_h  = takes((size_t)NB * ND);     short* mC_l  = takes((size_t)NB * ND);
    unsigned short* kbp_bf = (unsigned short*)s;
    unsigned short* knw_bf = kbp_bf + (size_t)NB * ND * NHW;

    // ---- prologue (R5): state copies + weight conversion ----
    hipMemcpyAsync(hist, history0, sizeof(float) * NB * ND * NK, hipMemcpyDeviceToDevice, stream);
    hipMemcpyAsync(wts,  wt0,      sizeof(float) * NB * NK,      hipMemcpyDeviceToDevice, stream);
    hipMemcpyAsync(bcat,       read_mem_b, sizeof(float) * 512, hipMemcpyDeviceToDevice, stream);
    hipMemcpyAsync(bcat + 512, rm_mem_b,   sizeof(float) * 512, hipMemcpyDeviceToDevice, stream);

    WTab tab;
    tab.s[0]  = {ctrl_pos_w, cpw_h, cpw_l, 2048 * 1024};
    tab.s[1]  = {ctrl_cq_w,  cqw_h, cqw_l, 512 * 1024};
    tab.s[2]  = {read_mem_w, wmc_h, wmc_l, 512 * 512};
    tab.s[3]  = {rm_mem_w,   wmc_h + 512 * 512, wmc_l + 512 * 512, 512 * 512};
    tab.s[4]  = {lr_w1,  lrw_h, lrw_l, 1024 * 1024};
    tab.s[5]  = {lrh_w1, lhw_h, lhw_l, 1024 * 1024};
    tab.s[6]  = {mix_w1, mxw_h, mxw_l, 512 * 512};
    tab.s[7]  = {write_w, ww_h, ww_l, 512 * 1024};
    tab.s[8]  = {question, q_h, q_l, 512 * 1024};
    tab.s[9]  = {control0, c0_h, c0_l, 512 * 512};
    tab.s[10] = {memory0,  m0_h, m0_l, 512 * 512};
    tab.s[11] = {nullptr, nullptr, nullptr, 0};
    tab.total = 2048*1024 + 512*1024 + 512*512 + 512*512 + 1024*1024 + 1024*1024
              + 512*512 + 512*1024 + 512*1024 + 512*512 + 512*512;
    wconv_k<<<dim3((tab.total + 255) / 256), dim3(256), 0, stream>>>(tab);
    tconv_k<<<dim3(32, 16, 2), dim3(256), 0, stream>>>(read_cat_w, read_attn_w, rcw_h, rcw_l,
                                                       rm_cat_w,  rm_attn_w,  rmw_h, rmw_l);

    auto P = [](const short* A1h, const short* A1l, int lda1, int k1,
                const short* A2h, const short* A2l, int lda2,
                const short* Bh, const short* Bl, const float* bias,
                float* C, short* Ch, short* Cl, int N, int K, int t0, int act) {
        GP q; q.A1h = A1h; q.A1l = A1l; q.A2h = A2h; q.A2l = A2l;
        q.Bh = Bh; q.Bl = Bl; q.bias = bias; q.C = C; q.Ch = Ch; q.Cl = Cl;
        q.lda1 = lda1; q.lda2 = lda2; q.k1 = k1; q.N = N; q.K = K;
        q.ntN = N / 64; q.t0 = t0; q.act = act;
        return q;
    };
    auto tilesOf = [](int N) { return (NB / 32) * (N / 64); };
    auto GG = [&](GPG g, int total) {
        ggemm_k<<<dim3(total), dim3(256), 0, stream>>>(g);
    };

    // pa for all 4 steps
    {
        GPG g; g.np = 1;
        g.p[0] = P(q_h, q_l, 1024, 1024, q_h, q_l, 1024, cpw_h, cpw_l, ctrl_pos_b,
                   nullptr, pa_h, pa_l, 2048, 1024, 0, 0);
        GG(g, tilesOf(2048));
    }
    // cqi_0
    {
        GPG g; g.np = 1;
        g.p[0] = P(c0_h, c0_l, ND, ND, pa_h, pa_l, 2048,
                   cqw_h, cqw_l, ctrl_cq_b, cqi, nullptr, nullptr, ND, 1024, 0, 0);
        GG(g, tilesOf(ND));
    }

    const short* mems_h[4] = {m0_h, mA_h, mB_h, mC_h};
    const short* mems_l[4] = {m0_l, mA_l, mB_l, mC_l};

    for (int i = 0; i < NSTEP; ++i) {
        // ---- A: write_{i-1} -> mems[i] (i>0) ----
        if (i > 0) {
            GPG g; g.np = 1;
            g.p[0] = P(cx_h, cx_l, ND, ND, mems_h[i - 1], mems_l[i - 1], ND,
                       ww_h, ww_l, write_b, nullptr,
                       (short*)mems_h[i], (short*)mems_l[i], ND, 1024, 0, 0);
            GG(g, tilesOf(ND));
        }
        // ---- B: control attention (control planes only) ----
        ctrl_attn_k<<<dim3(NB), dim3(512), 0, stream>>>(cqi, context, ctrl_attn_w, ct_h, ct_l);
        // ---- C: {mpc, u, uh, m1, cqi_{i+1}} — all depend only on mems[i]/ct/pa ----
        {
            GPG g; int nt = 0, np = 0;
            g.p[np++] = P(mems_h[i], mems_l[i], ND, ND, mems_h[i], mems_l[i], ND,
                          wmc_h, wmc_l, bcat, mpc, nullptr, nullptr, 1024, 512, nt, 0);
            nt += 256;
            g.p[np++] = P(ct_h, ct_l, ND, ND, ct_h, ct_l, ND,
                          rcw_h, rcw_l, nullptr, u, nullptr, nullptr, 1024, 512, nt, 0);
            nt += 256;
            g.p[np++] = P(ct_h, ct_l, ND, ND, ct_h, ct_l, ND,
                          rmw_h, rmw_l, nullptr, uh, nullptr, nullptr, 1024, 512, nt, 0);
            nt += 256;
            g.p[np++] = P(ct_h, ct_l, ND, ND, ct_h, ct_l, ND,
                          mxw_h, mxw_l, mix_b1, m1buf, nullptr, nullptr, 512, 512, nt, 1);
            nt += 128;
            if (i < NSTEP - 1) {
                g.p[np++] = P(ct_h, ct_l, ND, ND,
                              pa_h + (size_t)(i + 1) * ND, pa_l + (size_t)(i + 1) * ND, 2048,
                              cqw_h, cqw_l, ctrl_cq_b, cqi, nullptr, nullptr, ND, 1024, nt, 0);
                nt += 128;
            }
            g.np = np;
            GG(g, nt);
        }
        // ---- D: kb scores + hist attention ----
        if (i == 0)
            kbsh_k<1><<<dim3(5 * NB), dim3(256), 0, stream>>>(kb_proj, kbp_bf, mpc, u, s_part,
                                                              hist, uh, rvi, read_h, rh_h, rh_l);
        else
            kbsh_k<0><<<dim3(5 * NB), dim3(256), 0, stream>>>(kb_proj, kbp_bf, mpc, u, s_part,
                                                              hist, uh, rvi, read_h, rh_h, rh_l);
        // ---- E: kb softmax + read ----
        if (i == 0)
            kb_read_k<1><<<dim3(8, NB), dim3(256), 0, stream>>>(knowledge, knw_bf, s_part,
                                                                readv, rv_h, rv_l);
        else
            kb_read_k<0><<<dim3(8, NB), dim3(256), 0, stream>>>(knowledge, knw_bf, s_part,
                                                                readv, rv_h, rv_l);
        // ---- F: {g1a, g1b} (ELU) ----
        {
            GPG g; g.np = 2;
            g.p[0] = P(ct_h, ct_l, ND, ND, rv_h, rv_l, ND,
                       lrw_h, lrw_l, lr_b1, g1a, nullptr, nullptr, 1024, 1024, 0, 1);
            g.p[1] = P(ct_h, ct_l, ND, ND, rh_h, rh_l, ND,
                       lhw_h, lhw_l, lrh_b1, g1b, nullptr, nullptr, 1024, 1024, 256, 1);
            GG(g, 512);
        }
        // ---- G: scalars + state update ----
        update2_k<<<dim3(NB), dim3(256), 0, stream>>>(g1a, g1b, m1buf,
                                                      lr_w2, lr_b2, lrh_w2, lrh_b2,
                                                      mix_w2, mix_b2, rvi, readv, read_h,
                                                      hist, wts, cx_h, cx_l);
    }
    // ---- final write -> d_out ----
    {
        GPG g; g.np = 1;
        g.p[0] = P(cx_h, cx_l, ND, ND, mems_h[3], mems_l[3], ND,
                   ww_h, ww_l, write_b, (float*)d_out, nullptr, nullptr, ND, 1024, 0, 0);
        GG(g, tilesOf(ND));
    }
}

// Round 11
// 958.708 us; speedup vs baseline: 1.1095x; 1.0979x over previous
//
#include <hip/hip_runtime.h>
#include <cstddef>

constexpr int NB   = 512;  // batch
constexpr int ND   = 512;  // dim
constexpr int NL   = 32;   // context length
constexpr int NHW  = 196;  // knowledge spatial
constexpr int NK   = 8;    // history slots
constexpr int NSTEP = 4;

typedef __attribute__((ext_vector_type(8))) short short8v;
typedef __attribute__((ext_vector_type(4))) float f32x4;

// split x into bf16 hi + bf16 lo (residual), both round-to-nearest-even
__device__ __forceinline__ void splitbf(float x, short& h, short& l) {
    unsigned u  = __float_as_uint(x);
    unsigned hb = (u + 0x7FFFu + ((u >> 16) & 1u)) & 0xFFFF0000u;
    h = (short)(hb >> 16);
    float rem = x - __uint_as_float(hb);
    unsigned v = __float_as_uint(rem);
    l = (short)((v + 0x7FFFu + ((v >> 16) & 1u)) >> 16);
}
__device__ __forceinline__ unsigned short f2bf(float x) {
    unsigned u = __float_as_uint(x);
    return (unsigned short)((u + 0x7FFFu + ((u >> 16) & 1u)) >> 16);
}
__device__ __forceinline__ float bf2f(unsigned short h) {
    return __uint_as_float(((unsigned)h) << 16);
}

// =====================================================================
// LDS-staged grouped split-bf16 MFMA GEMM (BK=32, 3-pass, R5 exact).
// =====================================================================
struct GP {
    const short *A1h, *A1l, *A2h, *A2l, *Bh, *Bl;
    const float* bias;
    float* C; short* Ch; short* Cl;
    int lda1, lda2, k1, N, K, ntN, tile0;
};
struct GPG { GP p[3]; int np; };

template<int ACT>   // 0 none, 1 elu
__global__ __launch_bounds__(256) void ggemm_k(GPG g)
{
    __shared__ short Ah[32][40], Al[32][40], Bh_s[64][40], Bl_s[64][40];  // 15 KB
    const int flat = blockIdx.x;
    int pi = 0;
    if (g.np > 1 && flat >= g.p[1].tile0) pi = 1;
    if (g.np > 2 && flat >= g.p[2].tile0) pi = 2;
    const GP p = g.p[pi];
    const int local = flat - p.tile0;
    const int my = local / p.ntN, nx = local - my * p.ntN;
    const int m0 = my * 32, n0 = nx * 64;
    const int t = threadIdx.x, lane = t & 63, wid = t >> 6;
    const int wr = wid >> 1, wc = wid & 1;
    const int lr = lane & 15, lk = (lane >> 4) * 8;
    const int ar = (t & 127) >> 2, ak = (t & 3) * 8;
    const bool alo = t >= 128;
    const int br = t >> 2, bk = (t & 3) * 8;

    f32x4 acc0 = {}, acc1 = {};
    for (int kt = 0; kt < p.K; kt += 32) {
        {
            const int gk = kt + ak;
            const short* srcp = (gk < p.k1)
                ? (alo ? p.A1l : p.A1h) + (size_t)(m0 + ar) * p.lda1 + gk
                : (alo ? p.A2l : p.A2h) + (size_t)(m0 + ar) * p.lda2 + (gk - p.k1);
            short8v v = *(const short8v*)srcp;
            if (alo) *(short8v*)&Al[ar][ak] = v;
            else     *(short8v*)&Ah[ar][ak] = v;
        }
        {
            const size_t off = (size_t)(n0 + br) * p.K + kt + bk;
            *(short8v*)&Bh_s[br][bk] = *(const short8v*)(p.Bh + off);
            *(short8v*)&Bl_s[br][bk] = *(const short8v*)(p.Bl + off);
        }
        __syncthreads();
        short8v ah  = *(short8v*)&Ah[wr * 16 + lr][lk];
        short8v al  = *(short8v*)&Al[wr * 16 + lr][lk];
        short8v bh0 = *(short8v*)&Bh_s[wc * 32      + lr][lk];
        short8v bh1 = *(short8v*)&Bh_s[wc * 32 + 16 + lr][lk];
        short8v bl0 = *(short8v*)&Bl_s[wc * 32      + lr][lk];
        short8v bl1 = *(short8v*)&Bl_s[wc * 32 + 16 + lr][lk];
        acc0 = __builtin_amdgcn_mfma_f32_16x16x32_bf16(ah, bh0, acc0, 0, 0, 0);
        acc1 = __builtin_amdgcn_mfma_f32_16x16x32_bf16(ah, bh1, acc1, 0, 0, 0);
        acc0 = __builtin_amdgcn_mfma_f32_16x16x32_bf16(al, bh0, acc0, 0, 0, 0);
        acc1 = __builtin_amdgcn_mfma_f32_16x16x32_bf16(al, bh1, acc1, 0, 0, 0);
        acc0 = __builtin_amdgcn_mfma_f32_16x16x32_bf16(ah, bl0, acc0, 0, 0, 0);
        acc1 = __builtin_amdgcn_mfma_f32_16x16x32_bf16(ah, bl1, acc1, 0, 0, 0);
        __syncthreads();
    }
    const int r0 = m0 + wr * 16 + ((lane >> 4) << 2);
    const int cb = n0 + wc * 32 + lr;
    #pragma unroll
    for (int fc = 0; fc < 2; ++fc) {
        const f32x4& a = fc ? acc1 : acc0;
        const int col = cb + fc * 16;
        const float badd = p.bias ? p.bias[col] : 0.f;
        #pragma unroll
        for (int rr = 0; rr < 4; ++rr) {
            float x = a[rr] + badd;
            if (ACT == 1) x = (x > 0.f) ? x : (expf(x) - 1.f);
            const size_t idx = (size_t)(r0 + rr) * p.N + col;
            if (p.C) p.C[idx] = x;
            if (p.Ch) { short h, l; splitbf(x, h, l); p.Ch[idx] = h; p.Cl[idx] = l; }
        }
    }
}

// =====================================================================
// Weight/activation conversion prologue: fp32 -> bf16 hi/lo, 12 segments
// =====================================================================
struct WSeg { const float* src; short* dh; short* dl; int n; };
struct WTab { WSeg s[12]; int total; };

__global__ __launch_bounds__(256) void wconv_k(WTab tab)
{
    int i = blockIdx.x * 256 + threadIdx.x;
    if (i >= tab.total) return;
    int seg = 0, off = i;
    while (off >= tab.s[seg].n) { off -= tab.s[seg].n; ++seg; }
    short h, l; splitbf(tab.s[seg].src[off], h, l);
    tab.s[seg].dh[off] = h;
    tab.s[seg].dl[off] = l;
}

// Transpose-convert: src (512,1024) fp32 -> dst (1024,512) bf16 hi/lo
__global__ __launch_bounds__(256) void tconv_k(
    const float* s0, short* dh0, short* dl0,
    const float* s1, short* dh1, short* dl1)
{
    const float* src = blockIdx.z ? s1 : s0;
    short* dh = blockIdx.z ? dh1 : dh0;
    short* dl = blockIdx.z ? dl1 : dl0;
    __shared__ float tile[32][33];
    const int n0 = blockIdx.x * 32, k0 = blockIdx.y * 32;
    const int tx = threadIdx.x & 31, ty = threadIdx.x >> 5;
    for (int i = ty; i < 32; i += 8)
        tile[i][tx] = src[(size_t)(k0 + i) * 1024 + n0 + tx];
    __syncthreads();
    for (int i = ty; i < 32; i += 8) {
        short h, l; splitbf(tile[tx][i], h, l);
        dh[(size_t)(n0 + i) * 512 + k0 + tx] = h;
        dl[(size_t)(n0 + i) * 512 + k0 + tx] = l;
    }
}

// =====================================================================
// Control attention: emits hi/lo planes of control, cw, cwh.
// 512 threads, one block per batch element.
// =====================================================================
__global__ __launch_bounds__(512) void ctrl_attn_k(
    const float* __restrict__ cqi, const float* __restrict__ context,
    const float* __restrict__ attn_w, const float* __restrict__ read_attn_w,
    const float* __restrict__ rm_attn_w,
    short* __restrict__ ct_h, short* __restrict__ ct_l,
    short* __restrict__ cw_h, short* __restrict__ cw_l,
    short* __restrict__ cx_h, short* __restrict__ cx_l)
{
    const int b = blockIdx.x, t = threadIdx.x;
    const int lane = t & 63, w = t >> 6;
    __shared__ float q[ND];
    __shared__ float p[NL];
    const float* ctx = context + (size_t)b * NL * ND;

    q[t] = cqi[(size_t)b * ND + t] * attn_w[t];
    __syncthreads();

    for (int l = w; l < NL; l += 8) {
        float s = 0.f;
        const float* row = ctx + (size_t)l * ND;
        #pragma unroll
        for (int d = lane; d < ND; d += 64) s += q[d] * row[d];
        #pragma unroll
        for (int o = 32; o; o >>= 1) s += __shfl_down(s, o);
        if (lane == 0) p[l] = s;
    }
    __syncthreads();
    if (t == 0) {
        float mx = p[0];
        for (int l = 1; l < NL; ++l) mx = fmaxf(mx, p[l]);
        float sum = 0.f;
        for (int l = 0; l < NL; ++l) { float e = expf(p[l] - mx); p[l] = e; sum += e; }
        const float inv = 1.f / sum;
        for (int l = 0; l < NL; ++l) p[l] *= inv;
    }
    __syncthreads();
    float a = 0.f;
    #pragma unroll 8
    for (int l = 0; l < NL; ++l) a += p[l] * ctx[(size_t)l * ND + t];
    const size_t ix = (size_t)b * ND + t;
    short h, l2;
    splitbf(a, h, l2);                     ct_h[ix] = h; ct_l[ix] = l2;
    splitbf(a * read_attn_w[t], h, l2);    cw_h[ix] = h; cw_l[ix] = l2;
    splitbf(a * rm_attn_w[t],  h, l2);     cx_h[ix] = h; cx_l[ix] = l2;
}

// =====================================================================
// Merged kb_score + hist_attn.  FIRST=1: read kb_proj fp32, emit bf16.
//  blocks [0, 4*NB): kb partial scores;  [4*NB, 5*NB): history attention
// =====================================================================
template<int FIRST>
__global__ __launch_bounds__(256) void kbsh_k(
    const float* __restrict__ kbp_f32, unsigned short* __restrict__ kbp_bf,
    const float* __restrict__ mpc, const float* __restrict__ u,
    float* __restrict__ s_part,
    const float* __restrict__ hist, const float* __restrict__ uh,
    float* __restrict__ rvi, float* __restrict__ read_h,
    short* __restrict__ rh_h, short* __restrict__ rh_l)
{
    __shared__ float sh[NK * ND + ND];   // 18 KB
    __shared__ float sred[NK], pk[NK];
    const int bx = blockIdx.x, t = threadIdx.x;
    const int lane = t & 63, w = t >> 6;

    if (bx < 4 * NB) {
        // ---------------- kb_score ----------------
        const int jc = bx >> 9, b = bx & 511;
        float* v = sh;
        const int j0 = jc * 128;
        if (t < 128) {
            const int j = j0 + t;
            v[t] = mpc[(size_t)b * 1024 + j] * u[(size_t)b * 1024 + j]
                 + u[(size_t)b * 1024 + 512 + j];
        }
        __syncthreads();
        if (t < NHW) {
            const size_t base = (size_t)b * ND * NHW + (size_t)j0 * NHW + t;
            float s = 0.f;
            #pragma unroll 4
            for (int j = 0; j < 128; ++j) {
                float x;
                if (FIRST) {
                    x = kbp_f32[base + (size_t)j * NHW];
                    kbp_bf[base + (size_t)j * NHW] = f2bf(x);
                } else {
                    x = bf2f(kbp_bf[base + (size_t)j * NHW]);
                }
                s += x * v[j];
            }
            s_part[((size_t)jc * NB + b) * 200 + t] = s;
        }
    } else {
        // ---------------- hist_attn ----------------
        const int b = bx - 4 * NB;
        float* ht = sh;
        float* vh = sh + NK * ND;
        const float* hb = hist + (size_t)b * ND * NK;

        for (int dd = t; dd < ND; dd += 256) {
            float4 h0 = *(const float4*)&hb[(size_t)dd * NK];
            float4 h1 = *(const float4*)&hb[(size_t)dd * NK + 4];
            ht[0 * ND + dd] = h0.x; ht[1 * ND + dd] = h0.y;
            ht[2 * ND + dd] = h0.z; ht[3 * ND + dd] = h0.w;
            ht[4 * ND + dd] = h1.x; ht[5 * ND + dd] = h1.y;
            ht[6 * ND + dd] = h1.z; ht[7 * ND + dd] = h1.w;
            vh[dd] = mpc[(size_t)b * 1024 + 512 + dd] * uh[(size_t)b * 1024 + dd]
                   + uh[(size_t)b * 1024 + 512 + dd];
        }
        __syncthreads();

        for (int k = w; k < NK; k += 4) {
            float s = 0.f;
            #pragma unroll 4
            for (int dd = lane; dd < ND; dd += 64) s += ht[k * ND + dd] * vh[dd];
            #pragma unroll
            for (int o = 32; o; o >>= 1) s += __shfl_down(s, o);
            if (lane == 0) sred[k] = s;
        }
        __syncthreads();
        if (t == 0) {
            float mx = sred[0];
            #pragma unroll
            for (int k = 1; k < NK; ++k) mx = fmaxf(mx, sred[k]);
            float ev[NK]; float sum = 0.f;
            #pragma unroll
            for (int k = 0; k < NK; ++k) { ev[k] = expf(sred[k] - mx); sum += ev[k]; }
            const float inv = 1.f / sum;
            #pragma unroll
            for (int k = 0; k < NK; ++k) { float pv = ev[k] * inv; pk[k] = pv; rvi[(size_t)b * NK + k] = pv; }
        }
        __syncthreads();
        for (int dd = t; dd < ND; dd += 256) {
            float a = 0.f;
            #pragma unroll
            for (int k = 0; k < NK; ++k) a += pk[k] * ht[k * ND + dd];
            const size_t ix = (size_t)b * ND + dd;
            read_h[ix] = a;
            short h, l; splitbf(a, h, l);
            rh_h[ix] = h; rh_l[ix] = l;
        }
    }
}

// =====================================================================
// KB read: grid (8 d-chunks, B). FIRST=1: read knowledge fp32, emit bf16.
// =====================================================================
template<int FIRST>
__global__ __launch_bounds__(256) void kb_read_k(
    const float* __restrict__ knw_f32, unsigned short* __restrict__ knw_bf,
    const float* __restrict__ s_part,
    float* __restrict__ readv, short* __restrict__ rv_h, short* __restrict__ rv_l)
{
    const int dcb = blockIdx.x, b = blockIdx.y, t = threadIdx.x;
    const int lane = t & 63, w = t >> 6;
    __shared__ float ps[200];
    __shared__ float red[8];

    float val = -INFINITY;
    if (t < NHW) {
        float sp = 0.f;
        #pragma unroll
        for (int jc = 0; jc < 4; ++jc) sp += s_part[((size_t)jc * NB + b) * 200 + t];
        val = sp;
    }
    float mx = val;
    #pragma unroll
    for (int o = 32; o; o >>= 1) mx = fmaxf(mx, __shfl_xor(mx, o));
    if (lane == 0) red[w] = mx;
    __syncthreads();
    mx = fmaxf(fmaxf(red[0], red[1]), fmaxf(red[2], red[3]));
    const float e = (t < NHW) ? expf(val - mx) : 0.f;
    float sm = e;
    #pragma unroll
    for (int o = 32; o; o >>= 1) sm += __shfl_xor(sm, o);
    if (lane == 0) red[4 + w] = sm;
    __syncthreads();
    const float tot = red[4] + red[5] + red[6] + red[7];
    if (t < 200) ps[t] = (t < NHW) ? e / tot : 0.f;
    __syncthreads();

    const int d1 = dcb * 64 + 64;
    for (int d = dcb * 64 + w; d < d1; d += 4) {
        const size_t rbase = (size_t)b * ND * NHW + (size_t)d * NHW;
        float a = 0.f;
        for (int h = lane; h < NHW; h += 64) {
            float x;
            if (FIRST) {
                x = knw_f32[rbase + h];
                knw_bf[rbase + h] = f2bf(x);
            } else {
                x = bf2f(knw_bf[rbase + h]);
            }
            a += ps[h] * x;
        }
        #pragma unroll
        for (int o = 32; o; o >>= 1) a += __shfl_down(a, o);
        if (lane == 0) {
            const size_t ix = (size_t)b * ND + d;
            readv[ix] = a;
            short h2, l2; splitbf(a, h2, l2);
            rv_h[ix] = h2; rv_l[ix] = l2;
        }
    }
}

// =====================================================================
// Merged scalars + state update; emits ctx hi/lo planes.
// =====================================================================
__global__ __launch_bounds__(256) void update2_k(
    const float* __restrict__ g1a, const float* __restrict__ g1b,
    const float* __restrict__ m1,
    const float* __restrict__ lr_w2,  const float* __restrict__ lr_b2,
    const float* __restrict__ lrh_w2, const float* __restrict__ lrh_b2,
    const float* __restrict__ mix_w2, const float* __restrict__ mix_b2,
    const float* __restrict__ rvi, const float* __restrict__ readv,
    const float* __restrict__ read_h,
    float* __restrict__ hist, float* __restrict__ wts,
    short* __restrict__ ctx_h, short* __restrict__ ctx_l)
{
    const int b = blockIdx.x, t = threadIdx.x;
    const int lane = t & 63, w = t >> 6;
    __shared__ float red[4][5];
    __shared__ float sc[5];   // gk, gm, c0, c1, c2

    float pa = 0.f, pb = 0.f, p0 = 0.f, p1 = 0.f, p2 = 0.f;
    for (int k = t; k < 2 * ND; k += 256) {
        pa += g1a[(size_t)b * 2 * ND + k] * lr_w2[k];
        pb += g1b[(size_t)b * 2 * ND + k] * lrh_w2[k];
    }
    for (int d = t; d < ND; d += 256) {
        const float m = m1[(size_t)b * ND + d];
        p0 += m * mix_w2[d];
        p1 += m * mix_w2[ND + d];
        p2 += m * mix_w2[2 * ND + d];
    }
    #pragma unroll
    for (int o = 32; o; o >>= 1) {
        pa += __shfl_down(pa, o); pb += __shfl_down(pb, o);
        p0 += __shfl_down(p0, o); p1 += __shfl_down(p1, o); p2 += __shfl_down(p2, o);
    }
    if (lane == 0) { red[w][0] = pa; red[w][1] = pb; red[w][2] = p0; red[w][3] = p1; red[w][4] = p2; }
    __syncthreads();
    if (t == 0) {
        float sa = 0.f, sb = 0.f, s0 = 0.f, s1 = 0.f, s2 = 0.f;
        #pragma unroll
        for (int i = 0; i < 4; ++i) { sa += red[i][0]; sb += red[i][1]; s0 += red[i][2]; s1 += red[i][3]; s2 += red[i][4]; }
        sc[0] = 1.f / (1.f + expf(-(sa + lr_b2[0])));
        sc[1] = 1.f / (1.f + expf(-(sb + lrh_b2[0])));
        const float l0 = s0 + mix_b2[0], l1 = s1 + mix_b2[1], l2 = s2 + mix_b2[2];
        const float mx = fmaxf(l0, fmaxf(l1, l2));
        const float e0 = expf(l0 - mx), e1 = expf(l1 - mx), e2 = expf(l2 - mx);
        const float inv = 1.f / (e0 + e1 + e2);
        sc[2] = e0 * inv; sc[3] = e1 * inv; sc[4] = e2 * inv;
    }
    __syncthreads();

    const float gk = sc[0], gm = sc[1];
    const float c0 = sc[2], c1 = sc[3], c2 = sc[4];
    __shared__ float wo[NK], Ws[NK];
    if (t < NK) {
        const float w_old = wts[(size_t)b * NK + t];
        wo[t] = w_old;
        Ws[t] = (gm * rvi[(size_t)b * NK + t] + w_old * (1.f - gm)) * gk;
    }
    __syncthreads();
    float Wr[NK];
    #pragma unroll
    for (int k = 0; k < NK; ++k) Wr[k] = Ws[k];

    for (int dd = t; dd < ND; dd += 256) {
        const float rd = readv[(size_t)b * ND + dd];
        const float rh = read_h[(size_t)b * ND + dd];
        const float now = gk * rd, last = gm * rh;
        const float latest = (1.f - gk) * last + now;
        const float cr = c0 * now + c1 * last + c2 * latest;
        short h2, l2; splitbf(cr, h2, l2);
        ctx_h[(size_t)b * ND + dd] = h2;
        ctx_l[(size_t)b * ND + dd] = l2;
        float* hp = hist + (size_t)b * ND * NK + (size_t)dd * NK;
        float4 h0 = *(const float4*)&hp[0];
        float4 h1 = *(const float4*)&hp[4];
        h0.x = h0.x * (1.f - Wr[0]) + rd * Wr[0];
        h0.y = h0.y * (1.f - Wr[1]) + rd * Wr[1];
        h0.z = h0.z * (1.f - Wr[2]) + rd * Wr[2];
        h0.w = h0.w * (1.f - Wr[3]) + rd * Wr[3];
        h1.x = h1.x * (1.f - Wr[4]) + rd * Wr[4];
        h1.y = h1.y * (1.f - Wr[5]) + rd * Wr[5];
        h1.z = h1.z * (1.f - Wr[6]) + rd * Wr[6];
        h1.w = h1.w * (1.f - Wr[7]) + rd * Wr[7];
        *(float4*)&hp[0] = h0;
        *(float4*)&hp[4] = h1;
    }
    if (t == 0) {
        const float first = (1.f - gm) * gk;
        float nw[NK];
        #pragma unroll
        for (int k = 0; k < NK; ++k) nw[k] = wo[(k + 1) & 7] * first + wo[k] * (1.f - first);
        #pragma unroll
        for (int k = 0; k < NK; ++k) wts[(size_t)b * NK + k] = nw[k];
    }
}

// =====================================================================
extern "C" void kernel_launch(void* const* d_in, const int* in_sizes, int n_in,
                              void* d_out, int out_size, void* d_ws, size_t ws_size,
                              hipStream_t stream)
{
    (void)in_sizes; (void)n_in; (void)out_size; (void)ws_size;
    const float* context    = (const float*)d_in[0];
    const float* question   = (const float*)d_in[1];
    const float* knowledge  = (const float*)d_in[2];
    const float* kb_proj    = (const float*)d_in[3];
    const float* control0   = (const float*)d_in[4];
    const float* memory0    = (const float*)d_in[5];
    const float* history0   = (const float*)d_in[6];
    const float* wt0        = (const float*)d_in[7];
    const float* ctrl_pos_w = (const float*)d_in[8];
    const float* ctrl_pos_b = (const float*)d_in[9];
    const float* ctrl_cq_w  = (const float*)d_in[10];
    const float* ctrl_cq_b  = (const float*)d_in[11];
    const float* ctrl_attn_w= (const float*)d_in[12];
    const float* read_mem_w = (const float*)d_in[14];
    const float* read_mem_b = (const float*)d_in[15];
    const float* read_cat_w = (const float*)d_in[16];
    const float* read_attn_w= (const float*)d_in[18];
    const float* rm_mem_w   = (const float*)d_in[20];
    const float* rm_mem_b   = (const float*)d_in[21];
    const float* rm_cat_w   = (const float*)d_in[22];
    const float* rm_attn_w  = (const float*)d_in[24];
    const float* write_w    = (const float*)d_in[26];
    const float* write_b    = (const float*)d_in[27];
    const float* lr_w1      = (const float*)d_in[28];
    const float* lr_b1      = (const float*)d_in[29];
    const float* lr_w2      = (const float*)d_in[30];
    const float* lr_b2      = (const float*)d_in[31];
    const float* lrh_w1     = (const float*)d_in[32];
    const float* lrh_b1     = (const float*)d_in[33];
    const float* lrh_w2     = (const float*)d_in[34];
    const float* lrh_b2     = (const float*)d_in[35];
    const float* mix_w1     = (const float*)d_in[36];
    const float* mix_b1     = (const float*)d_in[37];
    const float* mix_w2     = (const float*)d_in[38];
    const float* mix_b2     = (const float*)d_in[39];

    // ---- workspace: fp32 region, then bf16 hi/lo shorts, then ushort kb ----
    float* f = (float*)d_ws;
    auto takef = [&](size_t n) { float* p = f; f += n; return p; };
    float* cqi    = takef((size_t)NB * ND);
    float* mpc    = takef((size_t)NB * 1024);   // [mem_p | memh]
    float* u      = takef((size_t)NB * 1024);
    float* uh     = takef((size_t)NB * 1024);
    float* readv  = takef((size_t)NB * ND);
    float* read_h = takef((size_t)NB * ND);
    float* rvi    = takef((size_t)NB * NK);
    float* g1a    = takef((size_t)NB * 1024);
    float* g1b    = takef((size_t)NB * 1024);
    float* m1buf  = takef((size_t)NB * ND);
    float* hist   = takef((size_t)NB * ND * NK);
    float* wts    = takef((size_t)NB * NK);
    float* s_part = takef((size_t)4 * NB * 200);
    float* bcat   = takef(1024);

    // align to 16B for short8 vector loads
    uintptr_t fa = ((uintptr_t)f + 15) & ~(uintptr_t)15;
    short* s = (short*)fa;
    auto takes = [&](size_t n) { short* p = s; s += n; return p; };
    // weights
    short* cpw_h = takes((size_t)2048 * 1024); short* cpw_l = takes((size_t)2048 * 1024);
    short* cqw_h = takes((size_t)512 * 1024);  short* cqw_l = takes((size_t)512 * 1024);
    short* wmc_h = takes((size_t)1024 * 512);  short* wmc_l = takes((size_t)1024 * 512);
    short* rcw_h = takes((size_t)1024 * 512);  short* rcw_l = takes((size_t)1024 * 512);
    short* rmw_h = takes((size_t)1024 * 512);  short* rmw_l = takes((size_t)1024 * 512);
    short* lrw_h = takes((size_t)1024 * 1024); short* lrw_l = takes((size_t)1024 * 1024);
    short* lhw_h = takes((size_t)1024 * 1024); short* lhw_l = takes((size_t)1024 * 1024);
    short* mxw_h = takes((size_t)512 * 512);   short* mxw_l = takes((size_t)512 * 512);
    short* ww_h  = takes((size_t)512 * 1024);  short* ww_l  = takes((size_t)512 * 1024);
    // activations (hi/lo planes)
    short* q_h   = takes((size_t)512 * 1024);  short* q_l   = takes((size_t)512 * 1024);
    short* c0_h  = takes((size_t)NB * ND);     short* c0_l  = takes((size_t)NB * ND);
    short* m0_h  = takes((size_t)NB * ND);     short* m0_l  = takes((size_t)NB * ND);
    short* pa_h  = takes((size_t)NB * 2048);   short* pa_l  = takes((size_t)NB * 2048);
    short* ct_h  = takes((size_t)NB * ND);     short* ct_l  = takes((size_t)NB * ND);
    short* cw_h  = takes((size_t)NB * ND);     short* cw_l  = takes((size_t)NB * ND);
    short* cwh_h = takes((size_t)NB * ND);     short* cwh_l = takes((size_t)NB * ND);
    short* rv_h  = takes((size_t)NB * ND);     short* rv_l  = takes((size_t)NB * ND);
    short* rh_h  = takes((size_t)NB * ND);     short* rh_l  = takes((size_t)NB * ND);
    short* cx_h  = takes((size_t)NB * ND);     short* cx_l  = takes((size_t)NB * ND);
    short* mA_h  = takes((size_t)NB * ND);     short* mA_l  = takes((size_t)NB * ND);
    short* mB_h  = takes((size_t)NB * ND);     short* mB_l  = takes((size_t)NB * ND);
    short* mC_h  = takes((size_t)NB * ND);     short* mC_l  = takes((size_t)NB * ND);
    // kb bf16 caches
    unsigned short* kbp_bf = (unsigned short*)s;
    unsigned short* knw_bf = kbp_bf + (size_t)NB * ND * NHW;

    // ---- prologue: state copies + conversions ----
    hipMemcpyAsync(hist, history0, sizeof(float) * NB * ND * NK, hipMemcpyDeviceToDevice, stream);
    hipMemcpyAsync(wts,  wt0,      sizeof(float) * NB * NK,      hipMemcpyDeviceToDevice, stream);
    hipMemcpyAsync(bcat,       read_mem_b, sizeof(float) * 512, hipMemcpyDeviceToDevice, stream);
    hipMemcpyAsync(bcat + 512, rm_mem_b,   sizeof(float) * 512, hipMemcpyDeviceToDevice, stream);

    WTab tab;
    tab.s[0]  = {ctrl_pos_w, cpw_h, cpw_l, 2048 * 1024};
    tab.s[1]  = {ctrl_cq_w,  cqw_h, cqw_l, 512 * 1024};
    tab.s[2]  = {read_mem_w, wmc_h, wmc_l, 512 * 512};
    tab.s[3]  = {rm_mem_w,   wmc_h + 512 * 512, wmc_l + 512 * 512, 512 * 512};
    tab.s[4]  = {lr_w1,  lrw_h, lrw_l, 1024 * 1024};
    tab.s[5]  = {lrh_w1, lhw_h, lhw_l, 1024 * 1024};
    tab.s[6]  = {mix_w1, mxw_h, mxw_l, 512 * 512};
    tab.s[7]  = {write_w, ww_h, ww_l, 512 * 1024};
    tab.s[8]  = {question, q_h, q_l, 512 * 1024};
    tab.s[9]  = {control0, c0_h, c0_l, 512 * 512};
    tab.s[10] = {memory0,  m0_h, m0_l, 512 * 512};
    tab.s[11] = {nullptr, nullptr, nullptr, 0};
    tab.total = 2048*1024 + 512*1024 + 512*512 + 512*512 + 1024*1024 + 1024*1024
              + 512*512 + 512*1024 + 512*1024 + 512*512 + 512*512;
    wconv_k<<<dim3((tab.total + 255) / 256), dim3(256), 0, stream>>>(tab);
    tconv_k<<<dim3(32, 16, 2), dim3(256), 0, stream>>>(read_cat_w, rcw_h, rcw_l,
                                                       rm_cat_w,  rmw_h, rmw_l);

    auto P = [](const short* A1h, const short* A1l, int lda1, int k1,
                const short* A2h, const short* A2l, int lda2,
                const short* Bh, const short* Bl, const float* bias,
                float* C, short* Ch, short* Cl, int N, int K, int tile0) {
        GP q; q.A1h = A1h; q.A1l = A1l; q.A2h = A2h; q.A2l = A2l;
        q.Bh = Bh; q.Bl = Bl; q.bias = bias; q.C = C; q.Ch = Ch; q.Cl = Cl;
        q.lda1 = lda1; q.lda2 = lda2; q.k1 = k1; q.N = N; q.K = K;
        q.ntN = N / 64; q.tile0 = tile0;
        return q;
    };
    auto tilesOf = [](int N) { return (NB / 32) * (N / 64); };
    auto GG = [&](GPG g, int total, int act) {
        if (act) ggemm_k<1><<<dim3(total), dim3(256), 0, stream>>>(g);
        else     ggemm_k<0><<<dim3(total), dim3(256), 0, stream>>>(g);
    };

    // pa for all 4 steps: (B,1024) @ ctrl_pos_w(2048,1024)^T -> hi/lo planes
    {
        GPG g; g.np = 1;
        g.p[0] = P(q_h, q_l, 1024, 1024, q_h, q_l, 1024, cpw_h, cpw_l, ctrl_pos_b,
                   nullptr, pa_h, pa_l, 2048, 1024, 0);
        GG(g, tilesOf(2048), 0);
    }

    const short* mems_h[4] = {m0_h, mA_h, mB_h, mC_h};
    const short* mems_l[4] = {m0_l, mA_l, mB_l, mC_l};
    const short* ctl_h = c0_h;
    const short* ctl_l = c0_l;

    for (int i = 0; i < NSTEP; ++i) {
        // ---- A: {write_{i-1} (if i>0)} + {cqi_i} ----
        {
            GPG g; int nt = 0, np = 0;
            if (i > 0) {
                g.p[np++] = P(cx_h, cx_l, ND, ND, mems_h[i - 1], mems_l[i - 1], ND,
                              ww_h, ww_l, write_b, nullptr,
                              (short*)mems_h[i], (short*)mems_l[i], ND, 1024, nt);
                nt += tilesOf(ND);
            }
            g.p[np++] = P(ctl_h, ctl_l, ND, ND, pa_h + (size_t)i * ND, pa_l + (size_t)i * ND, 2048,
                          cqw_h, cqw_l, ctrl_cq_b, cqi, nullptr, nullptr, ND, 1024, nt);
            nt += tilesOf(ND);
            g.np = np;
            GG(g, nt, 0);
        }
        // ---- B: control attention ----
        ctrl_attn_k<<<dim3(NB), dim3(512), 0, stream>>>(cqi, context, ctrl_attn_w,
                                                        read_attn_w, rm_attn_w,
                                                        ct_h, ct_l, cw_h, cw_l, cwh_h, cwh_l);
        ctl_h = ct_h; ctl_l = ct_l;
        // ---- C: {mpc, u, uh} ----
        {
            GPG g; g.np = 3;
            g.p[0] = P(mems_h[i], mems_l[i], ND, ND, mems_h[i], mems_l[i], ND,
                       wmc_h, wmc_l, bcat, mpc, nullptr, nullptr, 1024, 512, 0);
            g.p[1] = P(cw_h, cw_l, ND, ND, cw_h, cw_l, ND,
                       rcw_h, rcw_l, nullptr, u, nullptr, nullptr, 1024, 512, 256);
            g.p[2] = P(cwh_h, cwh_l, ND, ND, cwh_h, cwh_l, ND,
                       rmw_h, rmw_l, nullptr, uh, nullptr, nullptr, 1024, 512, 512);
            GG(g, 768, 0);
        }
        // ---- D: kb scores + hist attention ----
        if (i == 0)
            kbsh_k<1><<<dim3(5 * NB), dim3(256), 0, stream>>>(kb_proj, kbp_bf, mpc, u, s_part,
                                                              hist, uh, rvi, read_h, rh_h, rh_l);
        else
            kbsh_k<0><<<dim3(5 * NB), dim3(256), 0, stream>>>(kb_proj, kbp_bf, mpc, u, s_part,
                                                              hist, uh, rvi, read_h, rh_h, rh_l);
        // ---- E: kb softmax + read ----
        if (i == 0)
            kb_read_k<1><<<dim3(8, NB), dim3(256), 0, stream>>>(knowledge, knw_bf, s_part,
                                                                readv, rv_h, rv_l);
        else
            kb_read_k<0><<<dim3(8, NB), dim3(256), 0, stream>>>(knowledge, knw_bf, s_part,
                                                                readv, rv_h, rv_l);
        // ---- F: {g1a, g1b, m1} (ELU) ----
        {
            GPG g; g.np = 3;
            g.p[0] = P(ct_h, ct_l, ND, ND, rv_h, rv_l, ND,
                       lrw_h, lrw_l, lr_b1, g1a, nullptr, nullptr, 1024, 1024, 0);
            g.p[1] = P(ct_h, ct_l, ND, ND, rh_h, rh_l, ND,
                       lhw_h, lhw_l, lrh_b1, g1b, nullptr, nullptr, 1024, 1024, 256);
            g.p[2] = P(ct_h, ct_l, ND, ND, ct_h, ct_l, ND,
                       mxw_h, mxw_l, mix_b1, m1buf, nullptr, nullptr, 512, 512, 512);
            GG(g, 640, 1);
        }
        // ---- G: scalars + state update ----
        update2_k<<<dim3(NB), dim3(256), 0, stream>>>(g1a, g1b, m1buf,
                                                      lr_w2, lr_b2, lrh_w2, lrh_b2,
                                                      mix_w2, mix_b2, rvi, readv, read_h,
                                                      hist, wts, cx_h, cx_l);
    }
    // ---- final write -> d_out (fp32) ----
    {
        GPG g; g.np = 1;
        g.p[0] = P(cx_h, cx_l, ND, ND, mems_h[3], mems_l[3], ND,
                   ww_h, ww_l, write_b, (float*)d_out, nullptr, nullptr, ND, 1024, 0);
        GG(g, tilesOf(ND), 0);
    }
}